// Round 18
// baseline (141.966 us; speedup 1.0000x reference)
//
#include <hip/hip_runtime.h>

// Problem: B=4, T=2048, C=768, H=12, D=64.  qkv = x@w_qkv^T, rope(q,k),
// causal softmax(q k^T / 8) v, out = y@w_o^T.  All interface fp32; internal bf16.
#define B_  4
#define T_  2048
#define C_  768
#define H_  12
#define D_  64

typedef unsigned short u16;
typedef unsigned int   u32;
typedef __bf16 bf16;
typedef __bf16 bf16x4 __attribute__((ext_vector_type(4)));
typedef __bf16 bf16x8 __attribute__((ext_vector_type(8)));
typedef float  f32x4  __attribute__((ext_vector_type(4)));
typedef float  f32x16 __attribute__((ext_vector_type(16)));
typedef u32    u32x4  __attribute__((ext_vector_type(4)));
typedef __attribute__((address_space(1))) void* gas_t;
typedef __attribute__((address_space(3))) void* las_t;

static __device__ __forceinline__ u16 f2bf(float f) {
  u32 u = __builtin_bit_cast(u32, f);
  u += 0x7FFFu + ((u >> 16) & 1u);          // RNE
  return (u16)(u >> 16);
}

// v_cvt_pk_bf16_f32: dst.lo = bf16(a), dst.hi = bf16(b)  (RTNE)
static __device__ __forceinline__ u32 cvtpk(float a, float b) {
  u32 r;
  asm("v_cvt_pk_bf16_f32 %0, %1, %2" : "=v"(r) : "v"(a), "v"(b));
  return r;
}
// v_permlane32_swap_b32: a[32..63] <-> b[0..31]
static __device__ __forceinline__ void plswap(u32& a, u32& b) {
  asm volatile("v_permlane32_swap_b32 %0, %1" : "+v"(a), "+v"(b));
}

// ---------------- fp32 -> bf16 convert; w_qkv rows PERMUTED within each
// 64-row head group so the GEMM fragment holds rope pairs lane-locally:
// original col d -> fragment col c = ((d&1)|((d>>5)<<1))*16 + ((d>>1)&15.
__global__ __launch_bounds__(256) void k_cvt3(const float* __restrict__ a0,
                                              const float* __restrict__ a1,
                                              const float* __restrict__ a2,
                                              u16* __restrict__ o0,
                                              u16* __restrict__ o1,
                                              u16* __restrict__ o2) {
  const int bid = blockIdx.x;
  const int tid = threadIdx.x;
  if (bid < 6144) {                   // x: flat copy
    const int i = bid * 256 + tid;
    const float4 v = ((const float4*)a0)[i];
    ushort4 o;
    o.x = f2bf(v.x); o.y = f2bf(v.y); o.z = f2bf(v.z); o.w = f2bf(v.w);
    ((ushort4*)o0)[i] = o;
  } else if (bid < 7872) {            // w_qkv: row-permuted copy (q,k only)
    const int i = (bid - 6144) * 256 + tid;       // float4 index
    const int n = i / 192;                         // row (768/4 = 192 f4/row)
    const int c4 = i - n * 192;                    // float4 col within row
    int n2 = n;
    if (n < 1536) {
      const int d = n & 63;
      const int c = (((d & 1) | ((d >> 5) << 1)) << 4) | ((d >> 1) & 15);
      n2 = (n & ~63) | c;
    }
    const float4 v = ((const float4*)a1)[i];
    ushort4 o;
    o.x = f2bf(v.x); o.y = f2bf(v.y); o.z = f2bf(v.z); o.w = f2bf(v.w);
    ((ushort4*)o1)[n2 * 192 + c4] = o;
  } else {                            // w_o: flat copy
    const int i = (bid - 7872) * 256 + tid;
    const float4 v = ((const float4*)a2)[i];
    ushort4 o;
    o.x = f2bf(v.x); o.y = f2bf(v.y); o.z = f2bf(v.z); o.w = f2bf(v.w);
    ((ushort4*)o2)[i] = o;
  }
}

// ---------------- GEMM: C[m,n] = sum_k A[m,k]*Bt[n,k]  (bf16 in)
// BM=64, BN=128, BK=32, 4 waves (each 64r x 32c), 16x16x32 MFMA, XCD swizzle.
// TRIPLE-buffered (36 KB LDS -> 4 blocks/CU = 16 waves), 2-deep prefetch,
// single barrier + counted vmcnt(3) per K-step:
//   wait vmcnt(3) [tile ks landed; ks+1 stays in flight] ; s_barrier ;
//   STAGE(ks+2) ; COMPUTE(ks)
// LDS XOR-swizzle (row&3)<<4 on both staging source and read side (4-way max).
// MODE 1: f32 C out (grid 6x128).  MODE 2 (grid 18x128): fused qkv epilogue --
// rope+relayout q,k to (b,h,t,d) bf16 (q pre-scaled by 0.125*log2e), v to
// compact [b*T,768].  Wave w: head h2=(bx%6)*2+(w>>1), half hp=w&1; permuted
// cols keep rope pairs lane-local (pair=(acc[i][0],acc[i][1]), ip=hp*16+lo).
template<int MODE>
__global__ __launch_bounds__(256) void k_gemm_bt(const u16* __restrict__ A,
                                                 const u16* __restrict__ Bt,
                                                 float* __restrict__ Cout,
                                                 u16* __restrict__ qout,
                                                 u16* __restrict__ kout,
                                                 u16* __restrict__ vout,
                                                 const float* __restrict__ rope,
                                                 int M, int N, int K) {
  __shared__ u16 lA[3 * 64 * 32];
  __shared__ u16 lB[3 * 128 * 32];
  const int tid = threadIdx.x;
  const int l = tid & 63, w = tid >> 6;
  const int lo = l & 15, hi = l >> 4;
  const int wcol = w * 32;
  const int pid = blockIdx.x + gridDim.x * blockIdx.y;
  const int total = gridDim.x * gridDim.y;
  const int lid = (pid & 7) * (total >> 3) + (pid >> 3);
  const int bx = lid % gridDim.x, by = lid / gridDim.x;
  const int m0 = by * 64, n0 = bx * 128;

  // staging: 4 threads per 64-B row; thread covers swizzled byte col
  // scb = ((tid&3)*16) ^ ((row&3)<<4); dest linear (tid*8 elements/pass).
  const int srow_t = tid >> 2;                 // 0..63
  const int scb   = ((tid & 3) * 16) ^ ((srow_t & 3) << 4);
  const int swz   = (lo & 3) << 4;             // read-side XOR (row&3 == lo&3)

  auto STAGE = [&](int bufi, int k0) {
    __builtin_amdgcn_global_load_lds(
        (gas_t)(u16*)(A + (size_t)(m0 + srow_t) * K + k0 + (scb >> 1)),
        (las_t)(lA + bufi * 2048 + tid * 8), 16, 0, 0);
#pragma unroll
    for (int p = 0; p < 2; ++p)
      __builtin_amdgcn_global_load_lds(
          (gas_t)(u16*)(Bt + (size_t)(n0 + srow_t + 64 * p) * K + k0 + (scb >> 1)),
          (las_t)(lB + bufi * 4096 + p * 2048 + tid * 8), 16, 0, 0);
  };

  f32x4 acc[4][2] = {};
  auto COMPUTE = [&](const u16* la, const u16* lb) {
    const int co = ((hi * 16) ^ swz) >> 1;     // element col offset
    bf16x8 af[4], bfr[2];
#pragma unroll
    for (int i = 0; i < 4; ++i)
      af[i] = *(const bf16x8*)(la + (i * 16 + lo) * 32 + co);
#pragma unroll
    for (int j = 0; j < 2; ++j)
      bfr[j] = *(const bf16x8*)(lb + (wcol + j * 16 + lo) * 32 + co);
    __builtin_amdgcn_s_setprio(1);
#pragma unroll
    for (int i = 0; i < 4; ++i)
#pragma unroll
      for (int j = 0; j < 2; ++j)
        acc[i][j] = __builtin_amdgcn_mfma_f32_16x16x32_bf16(af[i], bfr[j], acc[i][j], 0, 0, 0);
    __builtin_amdgcn_s_setprio(0);
  };

  // 3-buffer, 2-deep prefetch K-loop (24 steps, K = 768)
  STAGE(0, 0);
  STAGE(1, 32);
  const int nk = K >> 5;
  int cur = 0;
  for (int ks = 0; ks < nk; ++ks) {
    if (ks + 1 < nk) asm volatile("s_waitcnt vmcnt(3)" ::: "memory");
    else             asm volatile("s_waitcnt vmcnt(0)" ::: "memory");
    __builtin_amdgcn_s_barrier();
    __builtin_amdgcn_sched_barrier(0);
    if (ks + 2 < nk) {
      int nb = cur + 2; if (nb >= 3) nb -= 3;
      STAGE(nb, (ks + 2) * 32);
    }
    COMPUTE(lA + cur * 2048, lB + cur * 4096);
    if (++cur == 3) cur = 0;
  }

  const int crow = m0;
  if (MODE == 1) {
#pragma unroll
    for (int i = 0; i < 4; ++i)
#pragma unroll
      for (int j = 0; j < 2; ++j)
#pragma unroll
        for (int r = 0; r < 4; ++r)
          Cout[(size_t)(crow + i * 16 + hi * 4 + r) * N + n0 + wcol + j * 16 + lo] = acc[i][j][r];
  } else {
    const int sect = bx / 6;              // 0 q, 1 k, 2 v
    const int h2 = (bx % 6) * 2 + (w >> 1);   // head 0..11
    const int hp = w & 1;                 // 32-col half of the head
    if (sect < 2) {
      // permuted cols: pair (acc[i][0][r], acc[i][1][r]) = x[d], x[d+1],
      // d = 2*ip, ip = hp*16 + lo (rope pair index)
      const float qsc = (sect == 0) ? 0.18033688011f : 1.0f;   // 0.125*log2(e)
      u16* dst = (sect == 0) ? qout : kout;
      const int ip = hp * 16 + lo;
#pragma unroll
      for (int i = 0; i < 4; ++i)
#pragma unroll
        for (int r = 0; r < 4; ++r) {
          const int trow = crow + i * 16 + hi * 4 + r;
          const int t = trow & (T_ - 1), bb = trow >> 11;
          const float2 cs = *(const float2*)(rope + ((size_t)t * 32 + ip) * 2);
          const float a0 = acc[i][0][r], a1 = acc[i][1][r];
          const float e0 = (a0 * cs.x - a1 * cs.y) * qsc;
          const float e1 = (a0 * cs.y + a1 * cs.x) * qsc;
          u16* row = dst + ((size_t)(bb * H_ + h2) * T_ + t) * D_;
          *(ushort2*)(row + 2 * ip) = make_ushort2(f2bf(e0), f2bf(e1));
        }
    } else {
      // v: unpermuted cols, write compact [trow][h2*64 + hp*32 + c]
#pragma unroll
      for (int i = 0; i < 4; ++i)
#pragma unroll
        for (int j = 0; j < 2; ++j)
#pragma unroll
          for (int r = 0; r < 4; ++r) {
            const int trow = crow + i * 16 + hi * 4 + r;
            vout[(size_t)trow * C_ + h2 * D_ + hp * 32 + j * 16 + lo] = f2bf(acc[i][j][r]);
          }
    }
  }
}

// ---------------- V transpose: compact v [b*T, 768] -> Vt (b,h,d,t)
__global__ __launch_bounds__(256) void k_vtrans(const u16* __restrict__ vtmp,
                                                u16* __restrict__ vt) {
  __shared__ u16 lds[64][68];
  const int bid = blockIdx.x;
  const int ttile = bid & 31, bh = bid >> 5;
  const int b = bh / H_, h = bh % H_;
  const int tid = threadIdx.x;
  const int tl = tid >> 2, doff = (tid & 3) * 16;
  const u16* src = vtmp + (size_t)(b * T_ + ttile * 64 + tl) * C_ + h * D_ + doff;
  const uint4 v0 = *(const uint4*)(src);
  const uint4 v1 = *(const uint4*)(src + 8);
  *(uint2*)&lds[tl][doff + 0]  = make_uint2(v0.x, v0.y);
  *(uint2*)&lds[tl][doff + 4]  = make_uint2(v0.z, v0.w);
  *(uint2*)&lds[tl][doff + 8]  = make_uint2(v1.x, v1.y);
  *(uint2*)&lds[tl][doff + 12] = make_uint2(v1.z, v1.w);
  __syncthreads();
  const int d = tl, toff = doff;
  uint4 o0, o1;
#define PK(j) ((u32)lds[toff + (j)][d] | ((u32)lds[toff + (j) + 1][d] << 16))
  o0.x = PK(0);  o0.y = PK(2);  o0.z = PK(4);  o0.w = PK(6);
  o1.x = PK(8);  o1.y = PK(10); o1.z = PK(12); o1.w = PK(14);
#undef PK
  u16* dst = vt + ((size_t)bh * D_ + d) * T_ + ttile * 64 + toff;
  *(uint4*)(dst) = o0;
  *(uint4*)(dst + 8) = o1;
}

// ---------------- flash attention v14: single barrier per kv-tile
// (unchanged -- uniform 33-tile blocks, kv-split waves, in-register P,
//  shift-free softmax, raw v_exp_f32, 4-way lsum)
__global__ __launch_bounds__(256) void k_attn(const u16* __restrict__ qb,
                                              const u16* __restrict__ kb,
                                              const u16* __restrict__ vtb,
                                              u16* __restrict__ yb) {
  __shared__ u16 kbuf[2][64 * 64];
  __shared__ u16 vbuf[2][64 * 64];
  __shared__ float obuf[2][64][33];      // stride 33 -> 2-way banking (free)
  __shared__ float lbuf[2][64];
  const int tid = threadIdx.x;
  const int w = tid >> 6, l = tid & 63;
  const int q5 = l & 31, hf = l >> 5;
  const int qg = w >> 1, st = w & 1;
  const int pid = blockIdx.x;
  const int xcd = pid & 7;
  const int rank = pid >> 3;                 // 0..95
  const int p = rank / 6;                    // 0..15 (segment pair)
  const int bh = xcd * 6 + rank % 6;         // 0..47 (6 heads per XCD L2)
  const int h = bh % H_, b = bh / H_;
  const u16* Q  = qb  + (size_t)bh * T_ * D_;
  const u16* K  = kb  + (size_t)bh * T_ * D_;
  const u16* Vt = vtb + (size_t)bh * D_ * T_;
  const int segA = 16 + p, segB = 15 - p;    // 64-q segment indices
  const int ntA = segA + 1;                  // tiles 0..segA; ntA+ntB = 33

  const int srow = tid >> 3;
  const int scb  = ((tid & 7) * 16) ^ ((srow & 7) << 4);
  const int swz  = (l & 7) << 4;

#define STAGE(bufi, j0s)                                                             \
  do {                                                                               \
    __builtin_amdgcn_global_load_lds((gas_t)(u16*)(K + (size_t)((j0s) + srow) * D_ + (scb >> 1)),      \
                                     (las_t)(&kbuf[bufi][0] + tid * 8), 16, 0, 0);   \
    __builtin_amdgcn_global_load_lds((gas_t)(u16*)(K + (size_t)((j0s) + 32 + srow) * D_ + (scb >> 1)), \
                                     (las_t)(&kbuf[bufi][0] + (tid + 256) * 8), 16, 0, 0);             \
    __builtin_amdgcn_global_load_lds((gas_t)(u16*)(Vt + (size_t)srow * T_ + (j0s) + (scb >> 1)),       \
                                     (las_t)(&vbuf[bufi][0] + tid * 8), 16, 0, 0);   \
    __builtin_amdgcn_global_load_lds((gas_t)(u16*)(Vt + (size_t)(32 + srow) * T_ + (j0s) + (scb >> 1)),\
                                     (las_t)(&vbuf[bufi][0] + (tid + 256) * 8), 16, 0, 0);             \
  } while (0)

  int seg = segA;
  int q0w = seg * 64 + qg * 32;
  int q = q0w + q5;                          // this lane's q column
  bf16x8 qf[4];
#pragma unroll
  for (int dc = 0; dc < 4; ++dc)
    qf[dc] = *(const bf16x8*)(Q + (size_t)q * D_ + dc * 16 + hf * 8);

  const f32x16 Z = {};
  f32x16 o0 = {}, o1 = {};                   // O^T rows d=0..31 / 32..63 (partial)
  float ls0 = 0.f, ls1 = 0.f, ls2 = 0.f, ls3 = 0.f;

  STAGE(0, 0);
  int cur = 0;
  for (int flat = 0; flat < 33; ++flat) {
    const int local = (flat < ntA) ? flat : flat - ntA;
    const int j0 = local * 64;
    // ---- single sync point: tile data ready AND prev-tile reads consumed
    asm volatile("s_waitcnt vmcnt(0)" ::: "memory");
    __builtin_amdgcn_s_barrier();
    __builtin_amdgcn_sched_barrier(0);
    if (flat + 1 < 33) {                     // prefetch next tile into buf^1
      const int nloc = (flat + 1 < ntA) ? flat + 1 : flat + 1 - ntA;
      STAGE(cur ^ 1, nloc * 64);
    }
    if (j0 + 32 * st <= q0w + 31) {          // wave has live kv columns
      const u16* kb_l = &kbuf[cur][0];
      const u16* vb_l = &vbuf[cur][0];
      // ---- QK^T: S[kv = j0+32st+row][q], chained over 4 d-chunks
      f32x16 s;
      __builtin_amdgcn_s_setprio(1);
      {
        const int krow = st * 32 + q5;
        const bf16x8 kd0 = *(const bf16x8*)(kb_l + krow * 64 + (((0  + 16 * hf) ^ swz) >> 1));
        s = __builtin_amdgcn_mfma_f32_32x32x16_bf16(kd0, qf[0], Z, 0, 0, 0);
        const bf16x8 kd1 = *(const bf16x8*)(kb_l + krow * 64 + (((32 + 16 * hf) ^ swz) >> 1));
        s = __builtin_amdgcn_mfma_f32_32x32x16_bf16(kd1, qf[1], s, 0, 0, 0);
        const bf16x8 kd2 = *(const bf16x8*)(kb_l + krow * 64 + (((64 + 16 * hf) ^ swz) >> 1));
        s = __builtin_amdgcn_mfma_f32_32x32x16_bf16(kd2, qf[2], s, 0, 0, 0);
        const bf16x8 kd3 = *(const bf16x8*)(kb_l + krow * 64 + (((96 + 16 * hf) ^ swz) >> 1));
        s = __builtin_amdgcn_mfma_f32_32x32x16_bf16(kd3, qf[3], s, 0, 0, 0);
      }
      __builtin_amdgcn_s_setprio(0);
      // ---- causal mask (diagonal tile only)
      if (local == seg) {
#pragma unroll
        for (int r = 0; r < 16; ++r) {
          const int kv = j0 + 32 * st + (r & 3) + 8 * (r >> 2) + 4 * hf;
          if (kv > q) s[r] = -1e30f;
        }
      }
      // ---- P = exp2(S) (q carries log2e/sqrt(D)); 4-way partial l
#pragma unroll
      for (int r = 0; r < 16; ++r)
        s[r] = __builtin_amdgcn_exp2f(s[r]);
#pragma unroll
      for (int r = 0; r < 16; r += 4) {
        ls0 += s[r]; ls1 += s[r + 1]; ls2 += s[r + 2]; ls3 += s[r + 3];
      }
      // ---- P -> bf16 PV B-fragments: cvt_pk + permlane32_swap
      u32 a0 = cvtpk(s[0],  s[1]),  b0 = cvtpk(s[4],  s[5]);  plswap(a0, b0);
      u32 a1 = cvtpk(s[2],  s[3]),  b1 = cvtpk(s[6],  s[7]);  plswap(a1, b1);
      u32 a2 = cvtpk(s[8],  s[9]),  b2 = cvtpk(s[12], s[13]); plswap(a2, b2);
      u32 a3 = cvtpk(s[10], s[11]), b3 = cvtpk(s[14], s[15]); plswap(a3, b3);
      const bf16x8 pa0 = __builtin_bit_cast(bf16x8, (u32x4){a0, a1, b0, b1});  // kv slot 2st
      const bf16x8 pa1 = __builtin_bit_cast(bf16x8, (u32x4){a2, a3, b2, b3});  // kv slot 2st+1
      // ---- PV: O^T[d][q] += Vt * P
      __builtin_amdgcn_s_setprio(1);
      {
        const int ks0 = st * 2, ks1 = st * 2 + 1;
        const bf16x8 vf00 = *(const bf16x8*)(vb_l + q5 * 64        + (((ks0 * 32 + 16 * hf) ^ swz) >> 1));
        const bf16x8 vf10 = *(const bf16x8*)(vb_l + (32 + q5) * 64 + (((ks0 * 32 + 16 * hf) ^ swz) >> 1));
        o0 = __builtin_amdgcn_mfma_f32_32x32x16_bf16(vf00, pa0, o0, 0, 0, 0);
        o1 = __builtin_amdgcn_mfma_f32_32x32x16_bf16(vf10, pa0, o1, 0, 0, 0);
        const bf16x8 vf01 = *(const bf16x8*)(vb_l + q5 * 64        + (((ks1 * 32 + 16 * hf) ^ swz) >> 1));
        const bf16x8 vf11 = *(const bf16x8*)(vb_l + (32 + q5) * 64 + (((ks1 * 32 + 16 * hf) ^ swz) >> 1));
        o0 = __builtin_amdgcn_mfma_f32_32x32x16_bf16(vf01, pa1, o0, 0, 0, 0);
        o1 = __builtin_amdgcn_mfma_f32_32x32x16_bf16(vf11, pa1, o1, 0, 0, 0);
      }
      __builtin_amdgcn_s_setprio(0);
    }
    // ---- segment end: combine kv-split partials (extra barrier, 2/block)
    if (local == seg) {
      if (st == 1) {                         // odd waves publish partials
        float* ob = &obuf[qg][l][0];
#pragma unroll
        for (int r = 0; r < 16; ++r) { ob[r] = o0[r]; ob[16 + r] = o1[r]; }
        float lr = (ls0 + ls1) + (ls2 + ls3);
        lr += __shfl_xor(lr, 32);
        lbuf[qg][l] = lr;
        asm volatile("s_waitcnt lgkmcnt(0)" ::: "memory");
      }
      asm volatile("" ::: "memory");
      __builtin_amdgcn_s_barrier();          // partials visible
      __builtin_amdgcn_sched_barrier(0);
      if (st == 0) {                         // even waves combine + store
        const float* ob = &obuf[qg][l][0];
#pragma unroll
        for (int r = 0; r < 16; ++r) { o0[r] += ob[r]; o1[r] += ob[16 + r]; }
        float lr = (ls0 + ls1) + (ls2 + ls3);
        lr += __shfl_xor(lr, 32);
        const float lt = lr + lbuf[qg][l];
        const float linv = 1.0f / lt;
        u16* yrow = yb + (size_t)(b * T_ + q) * C_ + h * D_;
#pragma unroll
        for (int g = 0; g < 4; ++g) {
          bf16x4 ok0, ok1;
#pragma unroll
          for (int r = 0; r < 4; ++r) {
            ok0[r] = (__bf16)(o0[4 * g + r] * linv);
            ok1[r] = (__bf16)(o1[4 * g + r] * linv);
          }
          *(bf16x4*)(yrow + g * 8 + 4 * hf)      = ok0;   // d = 8g+4hf+0..3
          *(bf16x4*)(yrow + 32 + g * 8 + 4 * hf) = ok1;   // d = 32+8g+4hf+0..3
        }
      }
      if (flat < 32) {                       // switch to light segment
        seg = segB;
        q0w = seg * 64 + qg * 32;
        q = q0w + q5;
#pragma unroll
        for (int dc = 0; dc < 4; ++dc)
          qf[dc] = *(const bf16x8*)(Q + (size_t)q * D_ + dc * 16 + hf * 8);
      }
      o0 = Z; o1 = Z;
      ls0 = 0.f; ls1 = 0.f; ls2 = 0.f; ls3 = 0.f;
    }
    cur ^= 1;
  }
#undef STAGE
}

extern "C" void kernel_launch(void* const* d_in, const int* in_sizes, int n_in,
                              void* d_out, int out_size, void* d_ws, size_t ws_size,
                              hipStream_t stream) {
  (void)in_sizes; (void)n_in; (void)out_size; (void)ws_size;
  const float* x    = (const float*)d_in[0];
  const float* rope = (const float*)d_in[1];
  const float* wqkv = (const float*)d_in[2];
  const float* wo   = (const float*)d_in[3];
  float* out = (float*)d_out;
  char* ws = (char*)d_ws;
  u16* xb    = (u16*)(ws);              // 12582912  (8192x768 bf16) -- reused as yb
  u16* wqkvb = (u16*)(ws + 12582912);   //  3538944  (2304x768, row-permuted)
  u16* wob   = (u16*)(ws + 16121856);   //  1179648  (768x768)
  u16* vtmp  = (u16*)(ws + 17301504);   // 12582912  (compact v [b*T,768])
  u16* qb    = (u16*)(ws + 55050240);   // 12582912  (b,h,t,d)
  u16* kb    = (u16*)(ws + 67633152);   // 12582912  (b,h,t,d)
  u16* vtb   = (u16*)(ws + 80216064);   // 12582912  (b,h,d,t)
  u16* yb    = xb;                      // x is dead after QKV GEMM

  k_cvt3<<<8448, 256, 0, stream>>>(x, wqkv, wo, xb, wqkvb, wob);
  k_gemm_bt<2><<<dim3(18, 128), 256, 0, stream>>>(xb, wqkvb, nullptr, qb, kb, vtmp,
                                                  rope, 8192, 2304, 768);
  k_vtrans<<<1536, 256, 0, stream>>>(vtmp, vtb);
  k_attn<<<768, 256, 0, stream>>>(qb, kb, vtb, yb);
  k_gemm_bt<1><<<dim3(6, 128), 256, 0, stream>>>(yb, wob, out, nullptr, nullptr, nullptr,
                                                 nullptr, 8192, 768, 768);
}

// Round 19
// 121.861 us; speedup vs baseline: 1.1650x; 1.1650x over previous
//
#include <hip/hip_runtime.h>

// Problem: B=4, T=2048, C=768, H=12, D=64.  qkv = x@w_qkv^T, rope(q,k),
// causal softmax(q k^T / 8) v, out = y@w_o^T.  All interface fp32; internal bf16.
#define B_  4
#define T_  2048
#define C_  768
#define H_  12
#define D_  64

typedef unsigned short u16;
typedef unsigned int   u32;
typedef __bf16 bf16;
typedef __bf16 bf16x4 __attribute__((ext_vector_type(4)));
typedef __bf16 bf16x8 __attribute__((ext_vector_type(8)));
typedef float  f32x4  __attribute__((ext_vector_type(4)));
typedef float  f32x16 __attribute__((ext_vector_type(16)));
typedef u32    u32x4  __attribute__((ext_vector_type(4)));
typedef __attribute__((address_space(1))) void* gas_t;
typedef __attribute__((address_space(3))) void* las_t;

static __device__ __forceinline__ u16 f2bf(float f) {
  u32 u = __builtin_bit_cast(u32, f);
  u += 0x7FFFu + ((u >> 16) & 1u);          // RNE
  return (u16)(u >> 16);
}

// v_cvt_pk_bf16_f32: dst.lo = bf16(a), dst.hi = bf16(b)  (RTNE)
static __device__ __forceinline__ u32 cvtpk(float a, float b) {
  u32 r;
  asm("v_cvt_pk_bf16_f32 %0, %1, %2" : "=v"(r) : "v"(a), "v"(b));
  return r;
}
// v_permlane32_swap_b32: a[32..63] <-> b[0..31]
static __device__ __forceinline__ void plswap(u32& a, u32& b) {
  asm volatile("v_permlane32_swap_b32 %0, %1" : "+v"(a), "+v"(b));
}

// ---------------- fp32 -> bf16 convert; w_qkv rows PERMUTED within each
// 64-row head group so the GEMM fragment holds rope pairs lane-locally:
// original col d -> fragment col c = ((d&1)|((d>>5)<<1))*16 + ((d>>1)&15.
__global__ __launch_bounds__(256) void k_cvt3(const float* __restrict__ a0,
                                              const float* __restrict__ a1,
                                              const float* __restrict__ a2,
                                              u16* __restrict__ o0,
                                              u16* __restrict__ o1,
                                              u16* __restrict__ o2) {
  const int bid = blockIdx.x;
  const int tid = threadIdx.x;
  if (bid < 6144) {                   // x: flat copy
    const int i = bid * 256 + tid;
    const float4 v = ((const float4*)a0)[i];
    ushort4 o;
    o.x = f2bf(v.x); o.y = f2bf(v.y); o.z = f2bf(v.z); o.w = f2bf(v.w);
    ((ushort4*)o0)[i] = o;
  } else if (bid < 7872) {            // w_qkv: row-permuted copy (q,k only)
    const int i = (bid - 6144) * 256 + tid;       // float4 index
    const int n = i / 192;                         // row (768/4 = 192 f4/row)
    const int c4 = i - n * 192;                    // float4 col within row
    int n2 = n;
    if (n < 1536) {
      const int d = n & 63;
      const int c = (((d & 1) | ((d >> 5) << 1)) << 4) | ((d >> 1) & 15);
      n2 = (n & ~63) | c;
    }
    const float4 v = ((const float4*)a1)[i];
    ushort4 o;
    o.x = f2bf(v.x); o.y = f2bf(v.y); o.z = f2bf(v.z); o.w = f2bf(v.w);
    ((ushort4*)o1)[n2 * 192 + c4] = o;
  } else {                            // w_o: flat copy
    const int i = (bid - 7872) * 256 + tid;
    const float4 v = ((const float4*)a2)[i];
    ushort4 o;
    o.x = f2bf(v.x); o.y = f2bf(v.y); o.z = f2bf(v.z); o.w = f2bf(v.w);
    ((ushort4*)o2)[i] = o;
  }
}

// ---------------- GEMM: C[m,n] = sum_k A[m,k]*Bt[n,k]  (bf16 in)
// BM=64, BN=128, BK=64, XOR-swizzled LDS, 4 waves (each 64r x 32c), 16x16x32
// MFMA, XCD swizzle.  Double-buffered, single-barrier protocol:
//   vmcnt(0) ; s_barrier ; STAGE(buf^1, next) ; COMPUTE(buf)
// 48 KB LDS -> 3 blocks/CU = 12 waves sustained.  (Round-18's BK=32
// triple-buffer variant regressed: doubled barrier count + 4-way conflicts.)
// MODE 1: f32 C out (grid 6x128).  MODE 2 (grid 18x128): fused qkv epilogue --
// rope+relayout q,k to (b,h,t,d) bf16 (q pre-scaled by 0.125*log2e), v to
// compact [b*T,768].  Wave w: head h2=(bx%6)*2+(w>>1), half hp=w&1; permuted
// cols keep rope pairs lane-local (pair=(acc[i][0],acc[i][1]), ip=hp*16+lo).
template<int MODE>
__global__ __launch_bounds__(256) void k_gemm_bt(const u16* __restrict__ A,
                                                 const u16* __restrict__ Bt,
                                                 float* __restrict__ Cout,
                                                 u16* __restrict__ qout,
                                                 u16* __restrict__ kout,
                                                 u16* __restrict__ vout,
                                                 const float* __restrict__ rope,
                                                 int M, int N, int K) {
  __shared__ u16 lA[2 * 64 * 64];
  __shared__ u16 lB[2 * 128 * 64];
  const int tid = threadIdx.x;
  const int l = tid & 63, w = tid >> 6;
  const int lo = l & 15, hi = l >> 4;
  const int wcol = w * 32;
  const int pid = blockIdx.x + gridDim.x * blockIdx.y;
  const int total = gridDim.x * gridDim.y;
  const int lid = (pid & 7) * (total >> 3) + (pid >> 3);
  const int bx = lid % gridDim.x, by = lid / gridDim.x;
  const int m0 = by * 64, n0 = bx * 128;

  // staging: thread t, pass p stages row (t>>3)+32p, 16B at swizzled source
  // col scb = ((t&7)*16) ^ ((row&7)<<4); dest linear (8t + 2048p elements).
  const int srow_t = tid >> 3;
  const int scb   = ((tid & 7) * 16) ^ ((srow_t & 7) << 4);
  const int swz   = (lo & 7) << 4;            // read-side XOR (row&7 == lo&7)

  auto STAGE = [&](int bufi, int k0) {
#pragma unroll
    for (int p = 0; p < 2; ++p)
      __builtin_amdgcn_global_load_lds(
          (gas_t)(u16*)(A + (size_t)(m0 + srow_t + 32 * p) * K + k0 + (scb >> 1)),
          (las_t)(lA + bufi * 64 * 64 + p * 2048 + tid * 8), 16, 0, 0);
#pragma unroll
    for (int p = 0; p < 4; ++p)
      __builtin_amdgcn_global_load_lds(
          (gas_t)(u16*)(Bt + (size_t)(n0 + srow_t + 32 * p) * K + k0 + (scb >> 1)),
          (las_t)(lB + bufi * 128 * 64 + p * 2048 + tid * 8), 16, 0, 0);
  };

  f32x4 acc[4][2] = {};
  auto COMPUTE = [&](const u16* la, const u16* lb) {
#pragma unroll
    for (int kk = 0; kk < 2; ++kk) {
      const int co = ((kk * 64 + hi * 16) ^ swz) >> 1;   // element col offset
      bf16x8 af[4], bfr[2];
#pragma unroll
      for (int i = 0; i < 4; ++i)
        af[i] = *(const bf16x8*)(la + (i * 16 + lo) * 64 + co);
#pragma unroll
      for (int j = 0; j < 2; ++j)
        bfr[j] = *(const bf16x8*)(lb + (wcol + j * 16 + lo) * 64 + co);
      __builtin_amdgcn_s_setprio(1);
#pragma unroll
      for (int i = 0; i < 4; ++i)
#pragma unroll
        for (int j = 0; j < 2; ++j)
          acc[i][j] = __builtin_amdgcn_mfma_f32_16x16x32_bf16(af[i], bfr[j], acc[i][j], 0, 0, 0);
      __builtin_amdgcn_s_setprio(0);
    }
  };

  // single-barrier double-buffered K-loop (12 steps, K = 768)
  STAGE(0, 0);
  int cur = 0;
  const int nk = K >> 6;
  for (int ks = 0; ks < nk; ++ks) {
    asm volatile("s_waitcnt vmcnt(0)" ::: "memory");
    __builtin_amdgcn_s_barrier();
    __builtin_amdgcn_sched_barrier(0);
    if (ks + 1 < nk) STAGE(cur ^ 1, (ks + 1) * 64);
    COMPUTE(lA + cur * 64 * 64, lB + cur * 128 * 64);
    cur ^= 1;
  }

  const int crow = m0;
  if (MODE == 1) {
#pragma unroll
    for (int i = 0; i < 4; ++i)
#pragma unroll
      for (int j = 0; j < 2; ++j)
#pragma unroll
        for (int r = 0; r < 4; ++r)
          Cout[(size_t)(crow + i * 16 + hi * 4 + r) * N + n0 + wcol + j * 16 + lo] = acc[i][j][r];
  } else {
    const int sect = bx / 6;              // 0 q, 1 k, 2 v
    const int h2 = (bx % 6) * 2 + (w >> 1);   // head 0..11
    const int hp = w & 1;                 // 32-col half of the head
    if (sect < 2) {
      // permuted cols: pair (acc[i][0][r], acc[i][1][r]) = x[d], x[d+1],
      // d = 2*ip, ip = hp*16 + lo (rope pair index)
      const float qsc = (sect == 0) ? 0.18033688011f : 1.0f;   // 0.125*log2(e)
      u16* dst = (sect == 0) ? qout : kout;
      const int ip = hp * 16 + lo;
#pragma unroll
      for (int i = 0; i < 4; ++i)
#pragma unroll
        for (int r = 0; r < 4; ++r) {
          const int trow = crow + i * 16 + hi * 4 + r;
          const int t = trow & (T_ - 1), bb = trow >> 11;
          const float2 cs = *(const float2*)(rope + ((size_t)t * 32 + ip) * 2);
          const float a0 = acc[i][0][r], a1 = acc[i][1][r];
          const float e0 = (a0 * cs.x - a1 * cs.y) * qsc;
          const float e1 = (a0 * cs.y + a1 * cs.x) * qsc;
          u16* row = dst + ((size_t)(bb * H_ + h2) * T_ + t) * D_;
          *(ushort2*)(row + 2 * ip) = make_ushort2(f2bf(e0), f2bf(e1));
        }
    } else {
      // v: unpermuted cols, write compact [trow][h2*64 + hp*32 + c]
#pragma unroll
      for (int i = 0; i < 4; ++i)
#pragma unroll
        for (int j = 0; j < 2; ++j)
#pragma unroll
          for (int r = 0; r < 4; ++r) {
            const int trow = crow + i * 16 + hi * 4 + r;
            vout[(size_t)trow * C_ + h2 * D_ + hp * 32 + j * 16 + lo] = f2bf(acc[i][j][r]);
          }
    }
  }
}

// ---------------- V transpose: compact v [b*T, 768] -> Vt (b,h,d,t)
__global__ __launch_bounds__(256) void k_vtrans(const u16* __restrict__ vtmp,
                                                u16* __restrict__ vt) {
  __shared__ u16 lds[64][68];
  const int bid = blockIdx.x;
  const int ttile = bid & 31, bh = bid >> 5;
  const int b = bh / H_, h = bh % H_;
  const int tid = threadIdx.x;
  const int tl = tid >> 2, doff = (tid & 3) * 16;
  const u16* src = vtmp + (size_t)(b * T_ + ttile * 64 + tl) * C_ + h * D_ + doff;
  const uint4 v0 = *(const uint4*)(src);
  const uint4 v1 = *(const uint4*)(src + 8);
  *(uint2*)&lds[tl][doff + 0]  = make_uint2(v0.x, v0.y);
  *(uint2*)&lds[tl][doff + 4]  = make_uint2(v0.z, v0.w);
  *(uint2*)&lds[tl][doff + 8]  = make_uint2(v1.x, v1.y);
  *(uint2*)&lds[tl][doff + 12] = make_uint2(v1.z, v1.w);
  __syncthreads();
  const int d = tl, toff = doff;
  uint4 o0, o1;
#define PK(j) ((u32)lds[toff + (j)][d] | ((u32)lds[toff + (j) + 1][d] << 16))
  o0.x = PK(0);  o0.y = PK(2);  o0.z = PK(4);  o0.w = PK(6);
  o1.x = PK(8);  o1.y = PK(10); o1.z = PK(12); o1.w = PK(14);
#undef PK
  u16* dst = vt + ((size_t)bh * D_ + d) * T_ + ttile * 64 + toff;
  *(uint4*)(dst) = o0;
  *(uint4*)(dst + 8) = o1;
}

// ---------------- flash attention v14: single barrier per kv-tile
// (unchanged -- uniform 33-tile blocks, kv-split waves, in-register P,
//  shift-free softmax, raw v_exp_f32, 4-way lsum)
__global__ __launch_bounds__(256) void k_attn(const u16* __restrict__ qb,
                                              const u16* __restrict__ kb,
                                              const u16* __restrict__ vtb,
                                              u16* __restrict__ yb) {
  __shared__ u16 kbuf[2][64 * 64];
  __shared__ u16 vbuf[2][64 * 64];
  __shared__ float obuf[2][64][33];      // stride 33 -> 2-way banking (free)
  __shared__ float lbuf[2][64];
  const int tid = threadIdx.x;
  const int w = tid >> 6, l = tid & 63;
  const int q5 = l & 31, hf = l >> 5;
  const int qg = w >> 1, st = w & 1;
  const int pid = blockIdx.x;
  const int xcd = pid & 7;
  const int rank = pid >> 3;                 // 0..95
  const int p = rank / 6;                    // 0..15 (segment pair)
  const int bh = xcd * 6 + rank % 6;         // 0..47 (6 heads per XCD L2)
  const int h = bh % H_, b = bh / H_;
  const u16* Q  = qb  + (size_t)bh * T_ * D_;
  const u16* K  = kb  + (size_t)bh * T_ * D_;
  const u16* Vt = vtb + (size_t)bh * D_ * T_;
  const int segA = 16 + p, segB = 15 - p;    // 64-q segment indices
  const int ntA = segA + 1;                  // tiles 0..segA; ntA+ntB = 33

  const int srow = tid >> 3;
  const int scb  = ((tid & 7) * 16) ^ ((srow & 7) << 4);
  const int swz  = (l & 7) << 4;

#define STAGE(bufi, j0s)                                                             \
  do {                                                                               \
    __builtin_amdgcn_global_load_lds((gas_t)(u16*)(K + (size_t)((j0s) + srow) * D_ + (scb >> 1)),      \
                                     (las_t)(&kbuf[bufi][0] + tid * 8), 16, 0, 0);   \
    __builtin_amdgcn_global_load_lds((gas_t)(u16*)(K + (size_t)((j0s) + 32 + srow) * D_ + (scb >> 1)), \
                                     (las_t)(&kbuf[bufi][0] + (tid + 256) * 8), 16, 0, 0);             \
    __builtin_amdgcn_global_load_lds((gas_t)(u16*)(Vt + (size_t)srow * T_ + (j0s) + (scb >> 1)),       \
                                     (las_t)(&vbuf[bufi][0] + tid * 8), 16, 0, 0);   \
    __builtin_amdgcn_global_load_lds((gas_t)(u16*)(Vt + (size_t)(32 + srow) * T_ + (j0s) + (scb >> 1)),\
                                     (las_t)(&vbuf[bufi][0] + (tid + 256) * 8), 16, 0, 0);             \
  } while (0)

  int seg = segA;
  int q0w = seg * 64 + qg * 32;
  int q = q0w + q5;                          // this lane's q column
  bf16x8 qf[4];
#pragma unroll
  for (int dc = 0; dc < 4; ++dc)
    qf[dc] = *(const bf16x8*)(Q + (size_t)q * D_ + dc * 16 + hf * 8);

  const f32x16 Z = {};
  f32x16 o0 = {}, o1 = {};                   // O^T rows d=0..31 / 32..63 (partial)
  float ls0 = 0.f, ls1 = 0.f, ls2 = 0.f, ls3 = 0.f;

  STAGE(0, 0);
  int cur = 0;
  for (int flat = 0; flat < 33; ++flat) {
    const int local = (flat < ntA) ? flat : flat - ntA;
    const int j0 = local * 64;
    // ---- single sync point: tile data ready AND prev-tile reads consumed
    asm volatile("s_waitcnt vmcnt(0)" ::: "memory");
    __builtin_amdgcn_s_barrier();
    __builtin_amdgcn_sched_barrier(0);
    if (flat + 1 < 33) {                     // prefetch next tile into buf^1
      const int nloc = (flat + 1 < ntA) ? flat + 1 : flat + 1 - ntA;
      STAGE(cur ^ 1, nloc * 64);
    }
    if (j0 + 32 * st <= q0w + 31) {          // wave has live kv columns
      const u16* kb_l = &kbuf[cur][0];
      const u16* vb_l = &vbuf[cur][0];
      // ---- QK^T: S[kv = j0+32st+row][q], chained over 4 d-chunks
      f32x16 s;
      __builtin_amdgcn_s_setprio(1);
      {
        const int krow = st * 32 + q5;
        const bf16x8 kd0 = *(const bf16x8*)(kb_l + krow * 64 + (((0  + 16 * hf) ^ swz) >> 1));
        s = __builtin_amdgcn_mfma_f32_32x32x16_bf16(kd0, qf[0], Z, 0, 0, 0);
        const bf16x8 kd1 = *(const bf16x8*)(kb_l + krow * 64 + (((32 + 16 * hf) ^ swz) >> 1));
        s = __builtin_amdgcn_mfma_f32_32x32x16_bf16(kd1, qf[1], s, 0, 0, 0);
        const bf16x8 kd2 = *(const bf16x8*)(kb_l + krow * 64 + (((64 + 16 * hf) ^ swz) >> 1));
        s = __builtin_amdgcn_mfma_f32_32x32x16_bf16(kd2, qf[2], s, 0, 0, 0);
        const bf16x8 kd3 = *(const bf16x8*)(kb_l + krow * 64 + (((96 + 16 * hf) ^ swz) >> 1));
        s = __builtin_amdgcn_mfma_f32_32x32x16_bf16(kd3, qf[3], s, 0, 0, 0);
      }
      __builtin_amdgcn_s_setprio(0);
      // ---- causal mask (diagonal tile only)
      if (local == seg) {
#pragma unroll
        for (int r = 0; r < 16; ++r) {
          const int kv = j0 + 32 * st + (r & 3) + 8 * (r >> 2) + 4 * hf;
          if (kv > q) s[r] = -1e30f;
        }
      }
      // ---- P = exp2(S) (q carries log2e/sqrt(D)); 4-way partial l
#pragma unroll
      for (int r = 0; r < 16; ++r)
        s[r] = __builtin_amdgcn_exp2f(s[r]);
#pragma unroll
      for (int r = 0; r < 16; r += 4) {
        ls0 += s[r]; ls1 += s[r + 1]; ls2 += s[r + 2]; ls3 += s[r + 3];
      }
      // ---- P -> bf16 PV B-fragments: cvt_pk + permlane32_swap
      u32 a0 = cvtpk(s[0],  s[1]),  b0 = cvtpk(s[4],  s[5]);  plswap(a0, b0);
      u32 a1 = cvtpk(s[2],  s[3]),  b1 = cvtpk(s[6],  s[7]);  plswap(a1, b1);
      u32 a2 = cvtpk(s[8],  s[9]),  b2 = cvtpk(s[12], s[13]); plswap(a2, b2);
      u32 a3 = cvtpk(s[10], s[11]), b3 = cvtpk(s[14], s[15]); plswap(a3, b3);
      const bf16x8 pa0 = __builtin_bit_cast(bf16x8, (u32x4){a0, a1, b0, b1});  // kv slot 2st
      const bf16x8 pa1 = __builtin_bit_cast(bf16x8, (u32x4){a2, a3, b2, b3});  // kv slot 2st+1
      // ---- PV: O^T[d][q] += Vt * P
      __builtin_amdgcn_s_setprio(1);
      {
        const int ks0 = st * 2, ks1 = st * 2 + 1;
        const bf16x8 vf00 = *(const bf16x8*)(vb_l + q5 * 64        + (((ks0 * 32 + 16 * hf) ^ swz) >> 1));
        const bf16x8 vf10 = *(const bf16x8*)(vb_l + (32 + q5) * 64 + (((ks0 * 32 + 16 * hf) ^ swz) >> 1));
        o0 = __builtin_amdgcn_mfma_f32_32x32x16_bf16(vf00, pa0, o0, 0, 0, 0);
        o1 = __builtin_amdgcn_mfma_f32_32x32x16_bf16(vf10, pa0, o1, 0, 0, 0);
        const bf16x8 vf01 = *(const bf16x8*)(vb_l + q5 * 64        + (((ks1 * 32 + 16 * hf) ^ swz) >> 1));
        const bf16x8 vf11 = *(const bf16x8*)(vb_l + (32 + q5) * 64 + (((ks1 * 32 + 16 * hf) ^ swz) >> 1));
        o0 = __builtin_amdgcn_mfma_f32_32x32x16_bf16(vf01, pa1, o0, 0, 0, 0);
        o1 = __builtin_amdgcn_mfma_f32_32x32x16_bf16(vf11, pa1, o1, 0, 0, 0);
      }
      __builtin_amdgcn_s_setprio(0);
    }
    // ---- segment end: combine kv-split partials (extra barrier, 2/block)
    if (local == seg) {
      if (st == 1) {                         // odd waves publish partials
        float* ob = &obuf[qg][l][0];
#pragma unroll
        for (int r = 0; r < 16; ++r) { ob[r] = o0[r]; ob[16 + r] = o1[r]; }
        float lr = (ls0 + ls1) + (ls2 + ls3);
        lr += __shfl_xor(lr, 32);
        lbuf[qg][l] = lr;
        asm volatile("s_waitcnt lgkmcnt(0)" ::: "memory");
      }
      asm volatile("" ::: "memory");
      __builtin_amdgcn_s_barrier();          // partials visible
      __builtin_amdgcn_sched_barrier(0);
      if (st == 0) {                         // even waves combine + store
        const float* ob = &obuf[qg][l][0];
#pragma unroll
        for (int r = 0; r < 16; ++r) { o0[r] += ob[r]; o1[r] += ob[16 + r]; }
        float lr = (ls0 + ls1) + (ls2 + ls3);
        lr += __shfl_xor(lr, 32);
        const float lt = lr + lbuf[qg][l];
        const float linv = 1.0f / lt;
        u16* yrow = yb + (size_t)(b * T_ + q) * C_ + h * D_;
#pragma unroll
        for (int g = 0; g < 4; ++g) {
          bf16x4 ok0, ok1;
#pragma unroll
          for (int r = 0; r < 4; ++r) {
            ok0[r] = (__bf16)(o0[4 * g + r] * linv);
            ok1[r] = (__bf16)(o1[4 * g + r] * linv);
          }
          *(bf16x4*)(yrow + g * 8 + 4 * hf)      = ok0;   // d = 8g+4hf+0..3
          *(bf16x4*)(yrow + 32 + g * 8 + 4 * hf) = ok1;   // d = 32+8g+4hf+0..3
        }
      }
      if (flat < 32) {                       // switch to light segment
        seg = segB;
        q0w = seg * 64 + qg * 32;
        q = q0w + q5;
#pragma unroll
        for (int dc = 0; dc < 4; ++dc)
          qf[dc] = *(const bf16x8*)(Q + (size_t)q * D_ + dc * 16 + hf * 8);
      }
      o0 = Z; o1 = Z;
      ls0 = 0.f; ls1 = 0.f; ls2 = 0.f; ls3 = 0.f;
    }
    cur ^= 1;
  }
#undef STAGE
}

extern "C" void kernel_launch(void* const* d_in, const int* in_sizes, int n_in,
                              void* d_out, int out_size, void* d_ws, size_t ws_size,
                              hipStream_t stream) {
  (void)in_sizes; (void)n_in; (void)out_size; (void)ws_size;
  const float* x    = (const float*)d_in[0];
  const float* rope = (const float*)d_in[1];
  const float* wqkv = (const float*)d_in[2];
  const float* wo   = (const float*)d_in[3];
  float* out = (float*)d_out;
  char* ws = (char*)d_ws;
  u16* xb    = (u16*)(ws);              // 12582912  (8192x768 bf16) -- reused as yb
  u16* wqkvb = (u16*)(ws + 12582912);   //  3538944  (2304x768, row-permuted)
  u16* wob   = (u16*)(ws + 16121856);   //  1179648  (768x768)
  u16* vtmp  = (u16*)(ws + 17301504);   // 12582912  (compact v [b*T,768])
  u16* qb    = (u16*)(ws + 55050240);   // 12582912  (b,h,t,d)
  u16* kb    = (u16*)(ws + 67633152);   // 12582912  (b,h,t,d)
  u16* vtb   = (u16*)(ws + 80216064);   // 12582912  (b,h,d,t)
  u16* yb    = xb;                      // x is dead after QKV GEMM

  k_cvt3<<<8448, 256, 0, stream>>>(x, wqkv, wo, xb, wqkvb, wob);
  k_gemm_bt<2><<<dim3(18, 128), 256, 0, stream>>>(xb, wqkvb, nullptr, qb, kb, vtmp,
                                                  rope, 8192, 2304, 768);
  k_vtrans<<<1536, 256, 0, stream>>>(vtmp, vtb);
  k_attn<<<768, 256, 0, stream>>>(qb, kb, vtb, yb);
  k_gemm_bt<1><<<dim3(6, 128), 256, 0, stream>>>(yb, wob, out, nullptr, nullptr, nullptr,
                                                 nullptr, 8192, 768, 768);
}

// Round 20
// 121.717 us; speedup vs baseline: 1.1664x; 1.0012x over previous
//
#include <hip/hip_runtime.h>

// Problem: B=4, T=2048, C=768, H=12, D=64.  qkv = x@w_qkv^T, rope(q,k),
// causal softmax(q k^T / 8) v, out = y@w_o^T.  All interface fp32; internal bf16.
#define B_  4
#define T_  2048
#define C_  768
#define H_  12
#define D_  64

typedef unsigned short u16;
typedef unsigned int   u32;
typedef __bf16 bf16;
typedef __bf16 bf16x4 __attribute__((ext_vector_type(4)));
typedef __bf16 bf16x8 __attribute__((ext_vector_type(8)));
typedef float  f32x4  __attribute__((ext_vector_type(4)));
typedef float  f32x16 __attribute__((ext_vector_type(16)));
typedef u32    u32x4  __attribute__((ext_vector_type(4)));
typedef __attribute__((address_space(1))) void* gas_t;
typedef __attribute__((address_space(3))) void* las_t;

static __device__ __forceinline__ u16 f2bf(float f) {
  u32 u = __builtin_bit_cast(u32, f);
  u += 0x7FFFu + ((u >> 16) & 1u);          // RNE
  return (u16)(u >> 16);
}

// v_cvt_pk_bf16_f32: dst.lo = bf16(a), dst.hi = bf16(b)  (RTNE)
static __device__ __forceinline__ u32 cvtpk(float a, float b) {
  u32 r;
  asm("v_cvt_pk_bf16_f32 %0, %1, %2" : "=v"(r) : "v"(a), "v"(b));
  return r;
}
// v_permlane32_swap_b32: a[32..63] <-> b[0..31]
static __device__ __forceinline__ void plswap(u32& a, u32& b) {
  asm volatile("v_permlane32_swap_b32 %0, %1" : "+v"(a), "+v"(b));
}

// ---------------- fp32 -> bf16 convert; w_qkv rows PERMUTED within each
// 64-row head group so the GEMM fragment holds rope pairs lane-locally:
// original col d -> fragment col c = ((d&1)|((d>>5)<<1))*16 + ((d>>1)&15.
__global__ __launch_bounds__(256) void k_cvt3(const float* __restrict__ a0,
                                              const float* __restrict__ a1,
                                              const float* __restrict__ a2,
                                              u16* __restrict__ o0,
                                              u16* __restrict__ o1,
                                              u16* __restrict__ o2) {
  const int bid = blockIdx.x;
  const int tid = threadIdx.x;
  if (bid < 6144) {                   // x: flat copy
    const int i = bid * 256 + tid;
    const float4 v = ((const float4*)a0)[i];
    ushort4 o;
    o.x = f2bf(v.x); o.y = f2bf(v.y); o.z = f2bf(v.z); o.w = f2bf(v.w);
    ((ushort4*)o0)[i] = o;
  } else if (bid < 7872) {            // w_qkv: row-permuted copy (q,k only)
    const int i = (bid - 6144) * 256 + tid;       // float4 index
    const int n = i / 192;                         // row (768/4 = 192 f4/row)
    const int c4 = i - n * 192;                    // float4 col within row
    int n2 = n;
    if (n < 1536) {
      const int d = n & 63;
      const int c = (((d & 1) | ((d >> 5) << 1)) << 4) | ((d >> 1) & 15);
      n2 = (n & ~63) | c;
    }
    const float4 v = ((const float4*)a1)[i];
    ushort4 o;
    o.x = f2bf(v.x); o.y = f2bf(v.y); o.z = f2bf(v.z); o.w = f2bf(v.w);
    ((ushort4*)o1)[n2 * 192 + c4] = o;
  } else {                            // w_o: flat copy
    const int i = (bid - 7872) * 256 + tid;
    const float4 v = ((const float4*)a2)[i];
    ushort4 o;
    o.x = f2bf(v.x); o.y = f2bf(v.y); o.z = f2bf(v.z); o.w = f2bf(v.w);
    ((ushort4*)o2)[i] = o;
  }
}

// ---------------- GEMM: C[m,n] = sum_k A[m,k]*Bt[n,k]  (bf16 in)
// BM=64, BN=128, BK=64, XOR-swizzled LDS, 4 waves (each 64r x 32c), 16x16x32
// MFMA, XCD swizzle.  Double-buffered with the 2-barrier COUNTED-vmcnt
// schedule (r15's best out-GEMM config, now on both GEMMs):
//   STAGE(buf^1, ks+1) ; vmcnt(6)  [cur's 6 loads landed, next 6 in flight]
//   B1 ; COMPUTE(cur) ; B2
// 48 KB LDS -> 3 blocks/CU = 12 waves sustained; bank conflicts = 0.
// MODE 1: f32 C out (grid 6x128).  MODE 2 (grid 18x128): fused qkv epilogue --
// rope+relayout q,k to (b,h,t,d) bf16 (q pre-scaled by 0.125*log2e), v to
// compact [b*T,768].  Wave w: head h2=(bx%6)*2+(w>>1), half hp=w&1; permuted
// cols keep rope pairs lane-local (pair=(acc[i][0],acc[i][1]), ip=hp*16+lo).
template<int MODE>
__global__ __launch_bounds__(256) void k_gemm_bt(const u16* __restrict__ A,
                                                 const u16* __restrict__ Bt,
                                                 float* __restrict__ Cout,
                                                 u16* __restrict__ qout,
                                                 u16* __restrict__ kout,
                                                 u16* __restrict__ vout,
                                                 const float* __restrict__ rope,
                                                 int M, int N, int K) {
  __shared__ u16 lA[2 * 64 * 64];
  __shared__ u16 lB[2 * 128 * 64];
  const int tid = threadIdx.x;
  const int l = tid & 63, w = tid >> 6;
  const int lo = l & 15, hi = l >> 4;
  const int wcol = w * 32;
  const int pid = blockIdx.x + gridDim.x * blockIdx.y;
  const int total = gridDim.x * gridDim.y;
  const int lid = (pid & 7) * (total >> 3) + (pid >> 3);
  const int bx = lid % gridDim.x, by = lid / gridDim.x;
  const int m0 = by * 64, n0 = bx * 128;

  // staging: thread t, pass p stages row (t>>3)+32p, 16B at swizzled source
  // col scb = ((t&7)*16) ^ ((row&7)<<4); dest linear (8t + 2048p elements).
  const int srow_t = tid >> 3;
  const int scb   = ((tid & 7) * 16) ^ ((srow_t & 7) << 4);
  const int swz   = (lo & 7) << 4;            // read-side XOR (row&7 == lo&7)

  auto STAGE = [&](int bufi, int k0) {
#pragma unroll
    for (int p = 0; p < 2; ++p)
      __builtin_amdgcn_global_load_lds(
          (gas_t)(u16*)(A + (size_t)(m0 + srow_t + 32 * p) * K + k0 + (scb >> 1)),
          (las_t)(lA + bufi * 64 * 64 + p * 2048 + tid * 8), 16, 0, 0);
#pragma unroll
    for (int p = 0; p < 4; ++p)
      __builtin_amdgcn_global_load_lds(
          (gas_t)(u16*)(Bt + (size_t)(n0 + srow_t + 32 * p) * K + k0 + (scb >> 1)),
          (las_t)(lB + bufi * 128 * 64 + p * 2048 + tid * 8), 16, 0, 0);
  };

  f32x4 acc[4][2] = {};
  auto COMPUTE = [&](const u16* la, const u16* lb) {
#pragma unroll
    for (int kk = 0; kk < 2; ++kk) {
      const int co = ((kk * 64 + hi * 16) ^ swz) >> 1;   // element col offset
      bf16x8 af[4], bfr[2];
#pragma unroll
      for (int i = 0; i < 4; ++i)
        af[i] = *(const bf16x8*)(la + (i * 16 + lo) * 64 + co);
#pragma unroll
      for (int j = 0; j < 2; ++j)
        bfr[j] = *(const bf16x8*)(lb + (wcol + j * 16 + lo) * 64 + co);
      __builtin_amdgcn_s_setprio(1);
#pragma unroll
      for (int i = 0; i < 4; ++i)
#pragma unroll
        for (int j = 0; j < 2; ++j)
          acc[i][j] = __builtin_amdgcn_mfma_f32_16x16x32_bf16(af[i], bfr[j], acc[i][j], 0, 0, 0);
      __builtin_amdgcn_s_setprio(0);
    }
  };

  // 2-barrier counted-vmcnt double-buffered K-loop (12 steps, K = 768)
  STAGE(0, 0);
  int cur = 0;
  const int nk = K >> 6;
  for (int ks = 0; ks < nk; ++ks) {
    if (ks + 1 < nk) {
      STAGE(cur ^ 1, (ks + 1) * 64);        // 6 loads, kept in flight
      asm volatile("s_waitcnt vmcnt(6)" ::: "memory");
    } else {
      asm volatile("s_waitcnt vmcnt(0)" ::: "memory");
    }
    __builtin_amdgcn_s_barrier();           // B1: buf[cur] ready for all
    __builtin_amdgcn_sched_barrier(0);
    COMPUTE(lA + cur * 64 * 64, lB + cur * 128 * 64);
    asm volatile("" ::: "memory");
    __builtin_amdgcn_s_barrier();           // B2: buf[cur] reads consumed
    __builtin_amdgcn_sched_barrier(0);
    cur ^= 1;
  }

  const int crow = m0;
  if (MODE == 1) {
#pragma unroll
    for (int i = 0; i < 4; ++i)
#pragma unroll
      for (int j = 0; j < 2; ++j)
#pragma unroll
        for (int r = 0; r < 4; ++r)
          Cout[(size_t)(crow + i * 16 + hi * 4 + r) * N + n0 + wcol + j * 16 + lo] = acc[i][j][r];
  } else {
    const int sect = bx / 6;              // 0 q, 1 k, 2 v
    const int h2 = (bx % 6) * 2 + (w >> 1);   // head 0..11
    const int hp = w & 1;                 // 32-col half of the head
    if (sect < 2) {
      // permuted cols: pair (acc[i][0][r], acc[i][1][r]) = x[d], x[d+1],
      // d = 2*ip, ip = hp*16 + lo (rope pair index)
      const float qsc = (sect == 0) ? 0.18033688011f : 1.0f;   // 0.125*log2(e)
      u16* dst = (sect == 0) ? qout : kout;
      const int ip = hp * 16 + lo;
#pragma unroll
      for (int i = 0; i < 4; ++i)
#pragma unroll
        for (int r = 0; r < 4; ++r) {
          const int trow = crow + i * 16 + hi * 4 + r;
          const int t = trow & (T_ - 1), bb = trow >> 11;
          const float2 cs = *(const float2*)(rope + ((size_t)t * 32 + ip) * 2);
          const float a0 = acc[i][0][r], a1 = acc[i][1][r];
          const float e0 = (a0 * cs.x - a1 * cs.y) * qsc;
          const float e1 = (a0 * cs.y + a1 * cs.x) * qsc;
          u16* row = dst + ((size_t)(bb * H_ + h2) * T_ + t) * D_;
          *(ushort2*)(row + 2 * ip) = make_ushort2(f2bf(e0), f2bf(e1));
        }
    } else {
      // v: unpermuted cols, write compact [trow][h2*64 + hp*32 + c]
#pragma unroll
      for (int i = 0; i < 4; ++i)
#pragma unroll
        for (int j = 0; j < 2; ++j)
#pragma unroll
          for (int r = 0; r < 4; ++r) {
            const int trow = crow + i * 16 + hi * 4 + r;
            vout[(size_t)trow * C_ + h2 * D_ + hp * 32 + j * 16 + lo] = f2bf(acc[i][j][r]);
          }
    }
  }
}

// ---------------- V transpose: compact v [b*T, 768] -> Vt (b,h,d,t)
__global__ __launch_bounds__(256) void k_vtrans(const u16* __restrict__ vtmp,
                                                u16* __restrict__ vt) {
  __shared__ u16 lds[64][68];
  const int bid = blockIdx.x;
  const int ttile = bid & 31, bh = bid >> 5;
  const int b = bh / H_, h = bh % H_;
  const int tid = threadIdx.x;
  const int tl = tid >> 2, doff = (tid & 3) * 16;
  const u16* src = vtmp + (size_t)(b * T_ + ttile * 64 + tl) * C_ + h * D_ + doff;
  const uint4 v0 = *(const uint4*)(src);
  const uint4 v1 = *(const uint4*)(src + 8);
  *(uint2*)&lds[tl][doff + 0]  = make_uint2(v0.x, v0.y);
  *(uint2*)&lds[tl][doff + 4]  = make_uint2(v0.z, v0.w);
  *(uint2*)&lds[tl][doff + 8]  = make_uint2(v1.x, v1.y);
  *(uint2*)&lds[tl][doff + 12] = make_uint2(v1.z, v1.w);
  __syncthreads();
  const int d = tl, toff = doff;
  uint4 o0, o1;
#define PK(j) ((u32)lds[toff + (j)][d] | ((u32)lds[toff + (j) + 1][d] << 16))
  o0.x = PK(0);  o0.y = PK(2);  o0.z = PK(4);  o0.w = PK(6);
  o1.x = PK(8);  o1.y = PK(10); o1.z = PK(12); o1.w = PK(14);
#undef PK
  u16* dst = vt + ((size_t)bh * D_ + d) * T_ + ttile * 64 + toff;
  *(uint4*)(dst) = o0;
  *(uint4*)(dst + 8) = o1;
}

// ---------------- flash attention v14: single barrier per kv-tile
// (unchanged -- uniform 33-tile blocks, kv-split waves, in-register P,
//  shift-free softmax, raw v_exp_f32, 4-way lsum)
__global__ __launch_bounds__(256) void k_attn(const u16* __restrict__ qb,
                                              const u16* __restrict__ kb,
                                              const u16* __restrict__ vtb,
                                              u16* __restrict__ yb) {
  __shared__ u16 kbuf[2][64 * 64];
  __shared__ u16 vbuf[2][64 * 64];
  __shared__ float obuf[2][64][33];      // stride 33 -> 2-way banking (free)
  __shared__ float lbuf[2][64];
  const int tid = threadIdx.x;
  const int w = tid >> 6, l = tid & 63;
  const int q5 = l & 31, hf = l >> 5;
  const int qg = w >> 1, st = w & 1;
  const int pid = blockIdx.x;
  const int xcd = pid & 7;
  const int rank = pid >> 3;                 // 0..95
  const int p = rank / 6;                    // 0..15 (segment pair)
  const int bh = xcd * 6 + rank % 6;         // 0..47 (6 heads per XCD L2)
  const int h = bh % H_, b = bh / H_;
  const u16* Q  = qb  + (size_t)bh * T_ * D_;
  const u16* K  = kb  + (size_t)bh * T_ * D_;
  const u16* Vt = vtb + (size_t)bh * D_ * T_;
  const int segA = 16 + p, segB = 15 - p;    // 64-q segment indices
  const int ntA = segA + 1;                  // tiles 0..segA; ntA+ntB = 33

  const int srow = tid >> 3;
  const int scb  = ((tid & 7) * 16) ^ ((srow & 7) << 4);
  const int swz  = (l & 7) << 4;

#define STAGE(bufi, j0s)                                                             \
  do {                                                                               \
    __builtin_amdgcn_global_load_lds((gas_t)(u16*)(K + (size_t)((j0s) + srow) * D_ + (scb >> 1)),      \
                                     (las_t)(&kbuf[bufi][0] + tid * 8), 16, 0, 0);   \
    __builtin_amdgcn_global_load_lds((gas_t)(u16*)(K + (size_t)((j0s) + 32 + srow) * D_ + (scb >> 1)), \
                                     (las_t)(&kbuf[bufi][0] + (tid + 256) * 8), 16, 0, 0);             \
    __builtin_amdgcn_global_load_lds((gas_t)(u16*)(Vt + (size_t)srow * T_ + (j0s) + (scb >> 1)),       \
                                     (las_t)(&vbuf[bufi][0] + tid * 8), 16, 0, 0);   \
    __builtin_amdgcn_global_load_lds((gas_t)(u16*)(Vt + (size_t)(32 + srow) * T_ + (j0s) + (scb >> 1)),\
                                     (las_t)(&vbuf[bufi][0] + (tid + 256) * 8), 16, 0, 0);             \
  } while (0)

  int seg = segA;
  int q0w = seg * 64 + qg * 32;
  int q = q0w + q5;                          // this lane's q column
  bf16x8 qf[4];
#pragma unroll
  for (int dc = 0; dc < 4; ++dc)
    qf[dc] = *(const bf16x8*)(Q + (size_t)q * D_ + dc * 16 + hf * 8);

  const f32x16 Z = {};
  f32x16 o0 = {}, o1 = {};                   // O^T rows d=0..31 / 32..63 (partial)
  float ls0 = 0.f, ls1 = 0.f, ls2 = 0.f, ls3 = 0.f;

  STAGE(0, 0);
  int cur = 0;
  for (int flat = 0; flat < 33; ++flat) {
    const int local = (flat < ntA) ? flat : flat - ntA;
    const int j0 = local * 64;
    // ---- single sync point: tile data ready AND prev-tile reads consumed
    asm volatile("s_waitcnt vmcnt(0)" ::: "memory");
    __builtin_amdgcn_s_barrier();
    __builtin_amdgcn_sched_barrier(0);
    if (flat + 1 < 33) {                     // prefetch next tile into buf^1
      const int nloc = (flat + 1 < ntA) ? flat + 1 : flat + 1 - ntA;
      STAGE(cur ^ 1, nloc * 64);
    }
    if (j0 + 32 * st <= q0w + 31) {          // wave has live kv columns
      const u16* kb_l = &kbuf[cur][0];
      const u16* vb_l = &vbuf[cur][0];
      // ---- QK^T: S[kv = j0+32st+row][q], chained over 4 d-chunks
      f32x16 s;
      __builtin_amdgcn_s_setprio(1);
      {
        const int krow = st * 32 + q5;
        const bf16x8 kd0 = *(const bf16x8*)(kb_l + krow * 64 + (((0  + 16 * hf) ^ swz) >> 1));
        s = __builtin_amdgcn_mfma_f32_32x32x16_bf16(kd0, qf[0], Z, 0, 0, 0);
        const bf16x8 kd1 = *(const bf16x8*)(kb_l + krow * 64 + (((32 + 16 * hf) ^ swz) >> 1));
        s = __builtin_amdgcn_mfma_f32_32x32x16_bf16(kd1, qf[1], s, 0, 0, 0);
        const bf16x8 kd2 = *(const bf16x8*)(kb_l + krow * 64 + (((64 + 16 * hf) ^ swz) >> 1));
        s = __builtin_amdgcn_mfma_f32_32x32x16_bf16(kd2, qf[2], s, 0, 0, 0);
        const bf16x8 kd3 = *(const bf16x8*)(kb_l + krow * 64 + (((96 + 16 * hf) ^ swz) >> 1));
        s = __builtin_amdgcn_mfma_f32_32x32x16_bf16(kd3, qf[3], s, 0, 0, 0);
      }
      __builtin_amdgcn_s_setprio(0);
      // ---- causal mask (diagonal tile only)
      if (local == seg) {
#pragma unroll
        for (int r = 0; r < 16; ++r) {
          const int kv = j0 + 32 * st + (r & 3) + 8 * (r >> 2) + 4 * hf;
          if (kv > q) s[r] = -1e30f;
        }
      }
      // ---- P = exp2(S) (q carries log2e/sqrt(D)); 4-way partial l
#pragma unroll
      for (int r = 0; r < 16; ++r)
        s[r] = __builtin_amdgcn_exp2f(s[r]);
#pragma unroll
      for (int r = 0; r < 16; r += 4) {
        ls0 += s[r]; ls1 += s[r + 1]; ls2 += s[r + 2]; ls3 += s[r + 3];
      }
      // ---- P -> bf16 PV B-fragments: cvt_pk + permlane32_swap
      u32 a0 = cvtpk(s[0],  s[1]),  b0 = cvtpk(s[4],  s[5]);  plswap(a0, b0);
      u32 a1 = cvtpk(s[2],  s[3]),  b1 = cvtpk(s[6],  s[7]);  plswap(a1, b1);
      u32 a2 = cvtpk(s[8],  s[9]),  b2 = cvtpk(s[12], s[13]); plswap(a2, b2);
      u32 a3 = cvtpk(s[10], s[11]), b3 = cvtpk(s[14], s[15]); plswap(a3, b3);
      const bf16x8 pa0 = __builtin_bit_cast(bf16x8, (u32x4){a0, a1, b0, b1});  // kv slot 2st
      const bf16x8 pa1 = __builtin_bit_cast(bf16x8, (u32x4){a2, a3, b2, b3});  // kv slot 2st+1
      // ---- PV: O^T[d][q] += Vt * P
      __builtin_amdgcn_s_setprio(1);
      {
        const int ks0 = st * 2, ks1 = st * 2 + 1;
        const bf16x8 vf00 = *(const bf16x8*)(vb_l + q5 * 64        + (((ks0 * 32 + 16 * hf) ^ swz) >> 1));
        const bf16x8 vf10 = *(const bf16x8*)(vb_l + (32 + q5) * 64 + (((ks0 * 32 + 16 * hf) ^ swz) >> 1));
        o0 = __builtin_amdgcn_mfma_f32_32x32x16_bf16(vf00, pa0, o0, 0, 0, 0);
        o1 = __builtin_amdgcn_mfma_f32_32x32x16_bf16(vf10, pa0, o1, 0, 0, 0);
        const bf16x8 vf01 = *(const bf16x8*)(vb_l + q5 * 64        + (((ks1 * 32 + 16 * hf) ^ swz) >> 1));
        const bf16x8 vf11 = *(const bf16x8*)(vb_l + (32 + q5) * 64 + (((ks1 * 32 + 16 * hf) ^ swz) >> 1));
        o0 = __builtin_amdgcn_mfma_f32_32x32x16_bf16(vf01, pa1, o0, 0, 0, 0);
        o1 = __builtin_amdgcn_mfma_f32_32x32x16_bf16(vf11, pa1, o1, 0, 0, 0);
      }
      __builtin_amdgcn_s_setprio(0);
    }
    // ---- segment end: combine kv-split partials (extra barrier, 2/block)
    if (local == seg) {
      if (st == 1) {                         // odd waves publish partials
        float* ob = &obuf[qg][l][0];
#pragma unroll
        for (int r = 0; r < 16; ++r) { ob[r] = o0[r]; ob[16 + r] = o1[r]; }
        float lr = (ls0 + ls1) + (ls2 + ls3);
        lr += __shfl_xor(lr, 32);
        lbuf[qg][l] = lr;
        asm volatile("s_waitcnt lgkmcnt(0)" ::: "memory");
      }
      asm volatile("" ::: "memory");
      __builtin_amdgcn_s_barrier();          // partials visible
      __builtin_amdgcn_sched_barrier(0);
      if (st == 0) {                         // even waves combine + store
        const float* ob = &obuf[qg][l][0];
#pragma unroll
        for (int r = 0; r < 16; ++r) { o0[r] += ob[r]; o1[r] += ob[16 + r]; }
        float lr = (ls0 + ls1) + (ls2 + ls3);
        lr += __shfl_xor(lr, 32);
        const float lt = lr + lbuf[qg][l];
        const float linv = 1.0f / lt;
        u16* yrow = yb + (size_t)(b * T_ + q) * C_ + h * D_;
#pragma unroll
        for (int g = 0; g < 4; ++g) {
          bf16x4 ok0, ok1;
#pragma unroll
          for (int r = 0; r < 4; ++r) {
            ok0[r] = (__bf16)(o0[4 * g + r] * linv);
            ok1[r] = (__bf16)(o1[4 * g + r] * linv);
          }
          *(bf16x4*)(yrow + g * 8 + 4 * hf)      = ok0;   // d = 8g+4hf+0..3
          *(bf16x4*)(yrow + 32 + g * 8 + 4 * hf) = ok1;   // d = 32+8g+4hf+0..3
        }
      }
      if (flat < 32) {                       // switch to light segment
        seg = segB;
        q0w = seg * 64 + qg * 32;
        q = q0w + q5;
#pragma unroll
        for (int dc = 0; dc < 4; ++dc)
          qf[dc] = *(const bf16x8*)(Q + (size_t)q * D_ + dc * 16 + hf * 8);
      }
      o0 = Z; o1 = Z;
      ls0 = 0.f; ls1 = 0.f; ls2 = 0.f; ls3 = 0.f;
    }
    cur ^= 1;
  }
#undef STAGE
}

extern "C" void kernel_launch(void* const* d_in, const int* in_sizes, int n_in,
                              void* d_out, int out_size, void* d_ws, size_t ws_size,
                              hipStream_t stream) {
  (void)in_sizes; (void)n_in; (void)out_size; (void)ws_size;
  const float* x    = (const float*)d_in[0];
  const float* rope = (const float*)d_in[1];
  const float* wqkv = (const float*)d_in[2];
  const float* wo   = (const float*)d_in[3];
  float* out = (float*)d_out;
  char* ws = (char*)d_ws;
  u16* xb    = (u16*)(ws);              // 12582912  (8192x768 bf16) -- reused as yb
  u16* wqkvb = (u16*)(ws + 12582912);   //  3538944  (2304x768, row-permuted)
  u16* wob   = (u16*)(ws + 16121856);   //  1179648  (768x768)
  u16* vtmp  = (u16*)(ws + 17301504);   // 12582912  (compact v [b*T,768])
  u16* qb    = (u16*)(ws + 55050240);   // 12582912  (b,h,t,d)
  u16* kb    = (u16*)(ws + 67633152);   // 12582912  (b,h,t,d)
  u16* vtb   = (u16*)(ws + 80216064);   // 12582912  (b,h,d,t)
  u16* yb    = xb;                      // x is dead after QKV GEMM

  k_cvt3<<<8448, 256, 0, stream>>>(x, wqkv, wo, xb, wqkvb, wob);
  k_gemm_bt<2><<<dim3(18, 128), 256, 0, stream>>>(xb, wqkvb, nullptr, qb, kb, vtmp,
                                                  rope, 8192, 2304, 768);
  k_vtrans<<<1536, 256, 0, stream>>>(vtmp, vtb);
  k_attn<<<768, 256, 0, stream>>>(qb, kb, vtb, yb);
  k_gemm_bt<1><<<dim3(6, 128), 256, 0, stream>>>(yb, wob, out, nullptr, nullptr, nullptr,
                                                 nullptr, 8192, 768, 768);
}

// Round 22
// 116.006 us; speedup vs baseline: 1.2238x; 1.0492x over previous
//
#include <hip/hip_runtime.h>

// Problem: B=4, T=2048, C=768, H=12, D=64.  qkv = x@w_qkv^T, rope(q,k),
// causal softmax(q k^T / 8) v, out = y@w_o^T.  All interface fp32; internal bf16.
#define B_  4
#define T_  2048
#define C_  768
#define H_  12
#define D_  64

typedef unsigned short u16;
typedef unsigned int   u32;
typedef __bf16 bf16;
typedef __bf16 bf16x4 __attribute__((ext_vector_type(4)));
typedef __bf16 bf16x8 __attribute__((ext_vector_type(8)));
typedef float  f32x4  __attribute__((ext_vector_type(4)));
typedef float  f32x16 __attribute__((ext_vector_type(16)));
typedef u32    u32x4  __attribute__((ext_vector_type(4)));
typedef __attribute__((address_space(1))) void* gas_t;
typedef __attribute__((address_space(3))) void* las_t;

static __device__ __forceinline__ u16 f2bf(float f) {
  u32 u = __builtin_bit_cast(u32, f);
  u += 0x7FFFu + ((u >> 16) & 1u);          // RNE
  return (u16)(u >> 16);
}

// v_cvt_pk_bf16_f32: dst.lo = bf16(a), dst.hi = bf16(b)  (RTNE)
static __device__ __forceinline__ u32 cvtpk(float a, float b) {
  u32 r;
  asm("v_cvt_pk_bf16_f32 %0, %1, %2" : "=v"(r) : "v"(a), "v"(b));
  return r;
}
// v_permlane32_swap_b32: a[32..63] <-> b[0..31]
static __device__ __forceinline__ void plswap(u32& a, u32& b) {
  asm volatile("v_permlane32_swap_b32 %0, %1" : "+v"(a), "+v"(b));
}

// ---------------- fp32 -> bf16 convert; w_qkv rows PERMUTED within each
// 64-row head group so the GEMM fragment holds rope pairs lane-locally:
// original col d -> fragment col c = ((d&1)|((d>>5)<<1))*16 + ((d>>1)&15.
__global__ __launch_bounds__(256) void k_cvt3(const float* __restrict__ a0,
                                              const float* __restrict__ a1,
                                              const float* __restrict__ a2,
                                              u16* __restrict__ o0,
                                              u16* __restrict__ o1,
                                              u16* __restrict__ o2) {
  const int bid = blockIdx.x;
  const int tid = threadIdx.x;
  if (bid < 6144) {                   // x: flat copy
    const int i = bid * 256 + tid;
    const float4 v = ((const float4*)a0)[i];
    ushort4 o;
    o.x = f2bf(v.x); o.y = f2bf(v.y); o.z = f2bf(v.z); o.w = f2bf(v.w);
    ((ushort4*)o0)[i] = o;
  } else if (bid < 7872) {            // w_qkv: row-permuted copy (q,k only)
    const int i = (bid - 6144) * 256 + tid;       // float4 index
    const int n = i / 192;                         // row (768/4 = 192 f4/row)
    const int c4 = i - n * 192;                    // float4 col within row
    int n2 = n;
    if (n < 1536) {
      const int d = n & 63;
      const int c = (((d & 1) | ((d >> 5) << 1)) << 4) | ((d >> 1) & 15);
      n2 = (n & ~63) | c;
    }
    const float4 v = ((const float4*)a1)[i];
    ushort4 o;
    o.x = f2bf(v.x); o.y = f2bf(v.y); o.z = f2bf(v.z); o.w = f2bf(v.w);
    ((ushort4*)o1)[n2 * 192 + c4] = o;
  } else {                            // w_o: flat copy
    const int i = (bid - 7872) * 256 + tid;
    const float4 v = ((const float4*)a2)[i];
    ushort4 o;
    o.x = f2bf(v.x); o.y = f2bf(v.y); o.z = f2bf(v.z); o.w = f2bf(v.w);
    ((ushort4*)o2)[i] = o;
  }
}

// ---------------- GEMM: C[m,n] = sum_k A[m,k]*Bt[n,k]  (bf16 in)
// BM=64, BN=128, BK=64, XOR-swizzled LDS, 4 waves (each 64r x 32c), 16x16x32
// MFMA, XCD swizzle.  Double-buffered, 2-barrier counted-vmcnt(6) schedule.
// 48 KB LDS -> 3 blocks/CU = 12 waves sustained; bank conflicts = 0.
// MODE 1: f32 C out (grid 6x128).  MODE 2 (grid 18x128): fused qkv epilogue --
// rope+relayout q,k to (b,h,t,d) bf16 (q pre-scaled by 0.125*log2e);
// v-section TRANSPOSES in the (dead) B-staging LDS and writes Vt (b,h,d,t)
// directly -- the standalone vtrans kernel and vtmp buffer are eliminated.
template<int MODE>
__global__ __launch_bounds__(256) void k_gemm_bt(const u16* __restrict__ A,
                                                 const u16* __restrict__ Bt,
                                                 float* __restrict__ Cout,
                                                 u16* __restrict__ qout,
                                                 u16* __restrict__ kout,
                                                 u16* __restrict__ vtout,
                                                 const float* __restrict__ rope,
                                                 int M, int N, int K) {
  __shared__ u16 lA[2 * 64 * 64];
  __shared__ u16 lB[2 * 128 * 64];
  const int tid = threadIdx.x;
  const int l = tid & 63, w = tid >> 6;
  const int lo = l & 15, hi = l >> 4;
  const int wcol = w * 32;
  const int pid = blockIdx.x + gridDim.x * blockIdx.y;
  const int total = gridDim.x * gridDim.y;
  const int lid = (pid & 7) * (total >> 3) + (pid >> 3);
  const int bx = lid % gridDim.x, by = lid / gridDim.x;
  const int m0 = by * 64, n0 = bx * 128;

  // staging: thread t, pass p stages row (t>>3)+32p, 16B at swizzled source
  // col scb = ((t&7)*16) ^ ((row&7)<<4); dest linear (8t + 2048p elements).
  const int srow_t = tid >> 3;
  const int scb   = ((tid & 7) * 16) ^ ((srow_t & 7) << 4);
  const int swz   = (lo & 7) << 4;            // read-side XOR (row&7 == lo&7)

  auto STAGE = [&](int bufi, int k0) {
#pragma unroll
    for (int p = 0; p < 2; ++p)
      __builtin_amdgcn_global_load_lds(
          (gas_t)(u16*)(A + (size_t)(m0 + srow_t + 32 * p) * K + k0 + (scb >> 1)),
          (las_t)(lA + bufi * 64 * 64 + p * 2048 + tid * 8), 16, 0, 0);
#pragma unroll
    for (int p = 0; p < 4; ++p)
      __builtin_amdgcn_global_load_lds(
          (gas_t)(u16*)(Bt + (size_t)(n0 + srow_t + 32 * p) * K + k0 + (scb >> 1)),
          (las_t)(lB + bufi * 128 * 64 + p * 2048 + tid * 8), 16, 0, 0);
  };

  f32x4 acc[4][2] = {};
  auto COMPUTE = [&](const u16* la, const u16* lb) {
#pragma unroll
    for (int kk = 0; kk < 2; ++kk) {
      const int co = ((kk * 64 + hi * 16) ^ swz) >> 1;   // element col offset
      bf16x8 af[4], bfr[2];
#pragma unroll
      for (int i = 0; i < 4; ++i)
        af[i] = *(const bf16x8*)(la + (i * 16 + lo) * 64 + co);
#pragma unroll
      for (int j = 0; j < 2; ++j)
        bfr[j] = *(const bf16x8*)(lb + (wcol + j * 16 + lo) * 64 + co);
      __builtin_amdgcn_s_setprio(1);
#pragma unroll
      for (int i = 0; i < 4; ++i)
#pragma unroll
        for (int j = 0; j < 2; ++j)
          acc[i][j] = __builtin_amdgcn_mfma_f32_16x16x32_bf16(af[i], bfr[j], acc[i][j], 0, 0, 0);
      __builtin_amdgcn_s_setprio(0);
    }
  };

  // 2-barrier counted-vmcnt double-buffered K-loop (12 steps, K = 768)
  STAGE(0, 0);
  int cur = 0;
  const int nk = K >> 6;
  for (int ks = 0; ks < nk; ++ks) {
    if (ks + 1 < nk) {
      STAGE(cur ^ 1, (ks + 1) * 64);        // 6 loads, kept in flight
      asm volatile("s_waitcnt vmcnt(6)" ::: "memory");
    } else {
      asm volatile("s_waitcnt vmcnt(0)" ::: "memory");
    }
    __builtin_amdgcn_s_barrier();           // B1: buf[cur] ready for all
    __builtin_amdgcn_sched_barrier(0);
    COMPUTE(lA + cur * 64 * 64, lB + cur * 128 * 64);
    asm volatile("" ::: "memory");
    __builtin_amdgcn_s_barrier();           // B2: buf[cur] reads consumed
    __builtin_amdgcn_sched_barrier(0);
    cur ^= 1;
  }

  const int crow = m0;
  if (MODE == 1) {
#pragma unroll
    for (int i = 0; i < 4; ++i)
#pragma unroll
      for (int j = 0; j < 2; ++j)
#pragma unroll
        for (int r = 0; r < 4; ++r)
          Cout[(size_t)(crow + i * 16 + hi * 4 + r) * N + n0 + wcol + j * 16 + lo] = acc[i][j][r];
  } else {
    const int sect = bx / 6;              // 0 q, 1 k, 2 v  (uniform per block)
    if (sect < 2) {
      const int h2 = (bx % 6) * 2 + (w >> 1);   // head 0..11
      const int hp = w & 1;                 // 32-col half of the head
      // permuted cols: pair (acc[i][0][r], acc[i][1][r]) = x[d], x[d+1],
      // d = 2*ip, ip = hp*16 + lo (rope pair index)
      const float qsc = (sect == 0) ? 0.18033688011f : 1.0f;   // 0.125*log2(e)
      u16* dst = (sect == 0) ? qout : kout;
      const int ip = hp * 16 + lo;
#pragma unroll
      for (int i = 0; i < 4; ++i)
#pragma unroll
        for (int r = 0; r < 4; ++r) {
          const int trow = crow + i * 16 + hi * 4 + r;
          const int t = trow & (T_ - 1), bb = trow >> 11;
          const float2 cs = *(const float2*)(rope + ((size_t)t * 32 + ip) * 2);
          const float a0 = acc[i][0][r], a1 = acc[i][1][r];
          const float e0 = (a0 * cs.x - a1 * cs.y) * qsc;
          const float e1 = (a0 * cs.y + a1 * cs.x) * qsc;
          u16* row = dst + ((size_t)(bb * H_ + h2) * T_ + t) * D_;
          *(ushort2*)(row + 2 * ip) = make_ushort2(f2bf(e0), f2bf(e1));
        }
    } else {
      // v: transpose through LDS (reuse lB, dead after K-loop), write Vt
      // (b,h,d,t) directly.  lT layout [ncol 0..127][t 0..63], pad 72
      // (rows 16B-aligned: 144 B; write banking ~2-way).
      u16* lT = lB;
      const int bb = crow >> 11;            // batch index
      const int t0 = crow & (T_ - 1);       // t-tile start WITHIN the batch
      const int hb = (bx % 6) * 2;          // head pair base
#pragma unroll
      for (int i = 0; i < 4; ++i)
#pragma unroll
        for (int j = 0; j < 2; ++j)
#pragma unroll
          for (int r = 0; r < 4; ++r)
            lT[(wcol + j * 16 + lo) * 72 + i * 16 + hi * 4 + r] = f2bf(acc[i][j][r]);
      __syncthreads();                      // block-uniform path: safe
#pragma unroll
      for (int pss = 0; pss < 4; ++pss) {
        const int row = pss * 32 + (tid >> 3);    // ncol 0..127
        const int toff = (tid & 7) * 8;           // t offset within tile
        const u32x4 vv = *(const u32x4*)(lT + row * 72 + toff);
        u16* dst = vtout + ((size_t)(bb * H_ + hb + (row >> 6)) * D_ + (row & 63)) * T_
                   + t0 + toff;
        *(u32x4*)dst = vv;
      }
    }
  }
}

// ---------------- flash attention v14: single barrier per kv-tile
// (unchanged -- uniform 33-tile blocks, kv-split waves, in-register P,
//  shift-free softmax, raw v_exp_f32, 4-way lsum)
__global__ __launch_bounds__(256) void k_attn(const u16* __restrict__ qb,
                                              const u16* __restrict__ kb,
                                              const u16* __restrict__ vtb,
                                              u16* __restrict__ yb) {
  __shared__ u16 kbuf[2][64 * 64];
  __shared__ u16 vbuf[2][64 * 64];
  __shared__ float obuf[2][64][33];      // stride 33 -> 2-way banking (free)
  __shared__ float lbuf[2][64];
  const int tid = threadIdx.x;
  const int w = tid >> 6, l = tid & 63;
  const int q5 = l & 31, hf = l >> 5;
  const int qg = w >> 1, st = w & 1;
  const int pid = blockIdx.x;
  const int xcd = pid & 7;
  const int rank = pid >> 3;                 // 0..95
  const int p = rank / 6;                    // 0..15 (segment pair)
  const int bh = xcd * 6 + rank % 6;         // 0..47 (6 heads per XCD L2)
  const int h = bh % H_, b = bh / H_;
  const u16* Q  = qb  + (size_t)bh * T_ * D_;
  const u16* K  = kb  + (size_t)bh * T_ * D_;
  const u16* Vt = vtb + (size_t)bh * D_ * T_;
  const int segA = 16 + p, segB = 15 - p;    // 64-q segment indices
  const int ntA = segA + 1;                  // tiles 0..segA; ntA+ntB = 33

  const int srow = tid >> 3;
  const int scb  = ((tid & 7) * 16) ^ ((srow & 7) << 4);
  const int swz  = (l & 7) << 4;

#define STAGE(bufi, j0s)                                                             \
  do {                                                                               \
    __builtin_amdgcn_global_load_lds((gas_t)(u16*)(K + (size_t)((j0s) + srow) * D_ + (scb >> 1)),      \
                                     (las_t)(&kbuf[bufi][0] + tid * 8), 16, 0, 0);   \
    __builtin_amdgcn_global_load_lds((gas_t)(u16*)(K + (size_t)((j0s) + 32 + srow) * D_ + (scb >> 1)), \
                                     (las_t)(&kbuf[bufi][0] + (tid + 256) * 8), 16, 0, 0);             \
    __builtin_amdgcn_global_load_lds((gas_t)(u16*)(Vt + (size_t)srow * T_ + (j0s) + (scb >> 1)),       \
                                     (las_t)(&vbuf[bufi][0] + tid * 8), 16, 0, 0);   \
    __builtin_amdgcn_global_load_lds((gas_t)(u16*)(Vt + (size_t)(32 + srow) * T_ + (j0s) + (scb >> 1)),\
                                     (las_t)(&vbuf[bufi][0] + (tid + 256) * 8), 16, 0, 0);             \
  } while (0)

  int seg = segA;
  int q0w = seg * 64 + qg * 32;
  int q = q0w + q5;                          // this lane's q column
  bf16x8 qf[4];
#pragma unroll
  for (int dc = 0; dc < 4; ++dc)
    qf[dc] = *(const bf16x8*)(Q + (size_t)q * D_ + dc * 16 + hf * 8);

  const f32x16 Z = {};
  f32x16 o0 = {}, o1 = {};                   // O^T rows d=0..31 / 32..63 (partial)
  float ls0 = 0.f, ls1 = 0.f, ls2 = 0.f, ls3 = 0.f;

  STAGE(0, 0);
  int cur = 0;
  for (int flat = 0; flat < 33; ++flat) {
    const int local = (flat < ntA) ? flat : flat - ntA;
    const int j0 = local * 64;
    // ---- single sync point: tile data ready AND prev-tile reads consumed
    asm volatile("s_waitcnt vmcnt(0)" ::: "memory");
    __builtin_amdgcn_s_barrier();
    __builtin_amdgcn_sched_barrier(0);
    if (flat + 1 < 33) {                     // prefetch next tile into buf^1
      const int nloc = (flat + 1 < ntA) ? flat + 1 : flat + 1 - ntA;
      STAGE(cur ^ 1, nloc * 64);
    }
    if (j0 + 32 * st <= q0w + 31) {          // wave has live kv columns
      const u16* kb_l = &kbuf[cur][0];
      const u16* vb_l = &vbuf[cur][0];
      // ---- QK^T: S[kv = j0+32st+row][q], chained over 4 d-chunks
      f32x16 s;
      __builtin_amdgcn_s_setprio(1);
      {
        const int krow = st * 32 + q5;
        const bf16x8 kd0 = *(const bf16x8*)(kb_l + krow * 64 + (((0  + 16 * hf) ^ swz) >> 1));
        s = __builtin_amdgcn_mfma_f32_32x32x16_bf16(kd0, qf[0], Z, 0, 0, 0);
        const bf16x8 kd1 = *(const bf16x8*)(kb_l + krow * 64 + (((32 + 16 * hf) ^ swz) >> 1));
        s = __builtin_amdgcn_mfma_f32_32x32x16_bf16(kd1, qf[1], s, 0, 0, 0);
        const bf16x8 kd2 = *(const bf16x8*)(kb_l + krow * 64 + (((64 + 16 * hf) ^ swz) >> 1));
        s = __builtin_amdgcn_mfma_f32_32x32x16_bf16(kd2, qf[2], s, 0, 0, 0);
        const bf16x8 kd3 = *(const bf16x8*)(kb_l + krow * 64 + (((96 + 16 * hf) ^ swz) >> 1));
        s = __builtin_amdgcn_mfma_f32_32x32x16_bf16(kd3, qf[3], s, 0, 0, 0);
      }
      __builtin_amdgcn_s_setprio(0);
      // ---- causal mask (diagonal tile only)
      if (local == seg) {
#pragma unroll
        for (int r = 0; r < 16; ++r) {
          const int kv = j0 + 32 * st + (r & 3) + 8 * (r >> 2) + 4 * hf;
          if (kv > q) s[r] = -1e30f;
        }
      }
      // ---- P = exp2(S) (q carries log2e/sqrt(D)); 4-way partial l
#pragma unroll
      for (int r = 0; r < 16; ++r)
        s[r] = __builtin_amdgcn_exp2f(s[r]);
#pragma unroll
      for (int r = 0; r < 16; r += 4) {
        ls0 += s[r]; ls1 += s[r + 1]; ls2 += s[r + 2]; ls3 += s[r + 3];
      }
      // ---- P -> bf16 PV B-fragments: cvt_pk + permlane32_swap
      u32 a0 = cvtpk(s[0],  s[1]),  b0 = cvtpk(s[4],  s[5]);  plswap(a0, b0);
      u32 a1 = cvtpk(s[2],  s[3]),  b1 = cvtpk(s[6],  s[7]);  plswap(a1, b1);
      u32 a2 = cvtpk(s[8],  s[9]),  b2 = cvtpk(s[12], s[13]); plswap(a2, b2);
      u32 a3 = cvtpk(s[10], s[11]), b3 = cvtpk(s[14], s[15]); plswap(a3, b3);
      const bf16x8 pa0 = __builtin_bit_cast(bf16x8, (u32x4){a0, a1, b0, b1});  // kv slot 2st
      const bf16x8 pa1 = __builtin_bit_cast(bf16x8, (u32x4){a2, a3, b2, b3});  // kv slot 2st+1
      // ---- PV: O^T[d][q] += Vt * P
      __builtin_amdgcn_s_setprio(1);
      {
        const int ks0 = st * 2, ks1 = st * 2 + 1;
        const bf16x8 vf00 = *(const bf16x8*)(vb_l + q5 * 64        + (((ks0 * 32 + 16 * hf) ^ swz) >> 1));
        const bf16x8 vf10 = *(const bf16x8*)(vb_l + (32 + q5) * 64 + (((ks0 * 32 + 16 * hf) ^ swz) >> 1));
        o0 = __builtin_amdgcn_mfma_f32_32x32x16_bf16(vf00, pa0, o0, 0, 0, 0);
        o1 = __builtin_amdgcn_mfma_f32_32x32x16_bf16(vf10, pa0, o1, 0, 0, 0);
        const bf16x8 vf01 = *(const bf16x8*)(vb_l + q5 * 64        + (((ks1 * 32 + 16 * hf) ^ swz) >> 1));
        const bf16x8 vf11 = *(const bf16x8*)(vb_l + (32 + q5) * 64 + (((ks1 * 32 + 16 * hf) ^ swz) >> 1));
        o0 = __builtin_amdgcn_mfma_f32_32x32x16_bf16(vf01, pa1, o0, 0, 0, 0);
        o1 = __builtin_amdgcn_mfma_f32_32x32x16_bf16(vf11, pa1, o1, 0, 0, 0);
      }
      __builtin_amdgcn_s_setprio(0);
    }
    // ---- segment end: combine kv-split partials (extra barrier, 2/block)
    if (local == seg) {
      if (st == 1) {                         // odd waves publish partials
        float* ob = &obuf[qg][l][0];
#pragma unroll
        for (int r = 0; r < 16; ++r) { ob[r] = o0[r]; ob[16 + r] = o1[r]; }
        float lr = (ls0 + ls1) + (ls2 + ls3);
        lr += __shfl_xor(lr, 32);
        lbuf[qg][l] = lr;
        asm volatile("s_waitcnt lgkmcnt(0)" ::: "memory");
      }
      asm volatile("" ::: "memory");
      __builtin_amdgcn_s_barrier();          // partials visible
      __builtin_amdgcn_sched_barrier(0);
      if (st == 0) {                         // even waves combine + store
        const float* ob = &obuf[qg][l][0];
#pragma unroll
        for (int r = 0; r < 16; ++r) { o0[r] += ob[r]; o1[r] += ob[16 + r]; }
        float lr = (ls0 + ls1) + (ls2 + ls3);
        lr += __shfl_xor(lr, 32);
        const float lt = lr + lbuf[qg][l];
        const float linv = 1.0f / lt;
        u16* yrow = yb + (size_t)(b * T_ + q) * C_ + h * D_;
#pragma unroll
        for (int g = 0; g < 4; ++g) {
          bf16x4 ok0, ok1;
#pragma unroll
          for (int r = 0; r < 4; ++r) {
            ok0[r] = (__bf16)(o0[4 * g + r] * linv);
            ok1[r] = (__bf16)(o1[4 * g + r] * linv);
          }
          *(bf16x4*)(yrow + g * 8 + 4 * hf)      = ok0;   // d = 8g+4hf+0..3
          *(bf16x4*)(yrow + 32 + g * 8 + 4 * hf) = ok1;   // d = 32+8g+4hf+0..3
        }
      }
      if (flat < 32) {                       // switch to light segment
        seg = segB;
        q0w = seg * 64 + qg * 32;
        q = q0w + q5;
#pragma unroll
        for (int dc = 0; dc < 4; ++dc)
          qf[dc] = *(const bf16x8*)(Q + (size_t)q * D_ + dc * 16 + hf * 8);
      }
      o0 = Z; o1 = Z;
      ls0 = 0.f; ls1 = 0.f; ls2 = 0.f; ls3 = 0.f;
    }
    cur ^= 1;
  }
#undef STAGE
}

extern "C" void kernel_launch(void* const* d_in, const int* in_sizes, int n_in,
                              void* d_out, int out_size, void* d_ws, size_t ws_size,
                              hipStream_t stream) {
  (void)in_sizes; (void)n_in; (void)out_size; (void)ws_size;
  const float* x    = (const float*)d_in[0];
  const float* rope = (const float*)d_in[1];
  const float* wqkv = (const float*)d_in[2];
  const float* wo   = (const float*)d_in[3];
  float* out = (float*)d_out;
  char* ws = (char*)d_ws;
  u16* xb    = (u16*)(ws);              // 12582912  (8192x768 bf16) -- reused as yb
  u16* wqkvb = (u16*)(ws + 12582912);   //  3538944  (2304x768, row-permuted)
  u16* wob   = (u16*)(ws + 16121856);   //  1179648  (768x768)
  u16* qb    = (u16*)(ws + 55050240);   // 12582912  (b,h,t,d)
  u16* kb    = (u16*)(ws + 67633152);   // 12582912  (b,h,t,d)
  u16* vtb   = (u16*)(ws + 80216064);   // 12582912  (b,h,d,t), written by GEMM epilogue
  u16* yb    = xb;                      // x is dead after QKV GEMM

  k_cvt3<<<8448, 256, 0, stream>>>(x, wqkv, wo, xb, wqkvb, wob);
  k_gemm_bt<2><<<dim3(18, 128), 256, 0, stream>>>(xb, wqkvb, nullptr, qb, kb, vtb,
                                                  rope, 8192, 2304, 768);
  k_attn<<<768, 256, 0, stream>>>(qb, kb, vtb, yb);
  k_gemm_bt<1><<<dim3(6, 128), 256, 0, stream>>>(yb, wob, out, nullptr, nullptr, nullptr,
                                                 nullptr, 8192, 768, 768);
}

// Round 23
// 115.460 us; speedup vs baseline: 1.2296x; 1.0047x over previous
//
#include <hip/hip_runtime.h>

// Problem: B=4, T=2048, C=768, H=12, D=64.  qkv = x@w_qkv^T, rope(q,k),
// causal softmax(q k^T / 8) v, out = y@w_o^T.  All interface fp32; internal bf16.
#define B_  4
#define T_  2048
#define C_  768
#define H_  12
#define D_  64

typedef unsigned short u16;
typedef unsigned int   u32;
typedef __bf16 bf16;
typedef __bf16 bf16x4 __attribute__((ext_vector_type(4)));
typedef __bf16 bf16x8 __attribute__((ext_vector_type(8)));
typedef float  f32x4  __attribute__((ext_vector_type(4)));
typedef float  f32x16 __attribute__((ext_vector_type(16)));
typedef u32    u32x4  __attribute__((ext_vector_type(4)));
typedef __attribute__((address_space(1))) void* gas_t;
typedef __attribute__((address_space(3))) void* las_t;

static __device__ __forceinline__ u16 f2bf(float f) {
  u32 u = __builtin_bit_cast(u32, f);
  u += 0x7FFFu + ((u >> 16) & 1u);          // RNE
  return (u16)(u >> 16);
}

// v_cvt_pk_bf16_f32: dst.lo = bf16(a), dst.hi = bf16(b)  (RTNE)
static __device__ __forceinline__ u32 cvtpk(float a, float b) {
  u32 r;
  asm("v_cvt_pk_bf16_f32 %0, %1, %2" : "=v"(r) : "v"(a), "v"(b));
  return r;
}
// v_permlane32_swap_b32: a[32..63] <-> b[0..31]
static __device__ __forceinline__ void plswap(u32& a, u32& b) {
  asm volatile("v_permlane32_swap_b32 %0, %1" : "+v"(a), "+v"(b));
}

// ---------------- fp32 -> bf16 convert; w_qkv rows PERMUTED within each
// 64-row head group so the GEMM fragment holds rope pairs lane-locally:
// original col d -> fragment col c = ((d&1)|((d>>5)<<1))*16 + ((d>>1)&15.
__global__ __launch_bounds__(256) void k_cvt3(const float* __restrict__ a0,
                                              const float* __restrict__ a1,
                                              const float* __restrict__ a2,
                                              u16* __restrict__ o0,
                                              u16* __restrict__ o1,
                                              u16* __restrict__ o2) {
  const int bid = blockIdx.x;
  const int tid = threadIdx.x;
  if (bid < 6144) {                   // x: flat copy
    const int i = bid * 256 + tid;
    const float4 v = ((const float4*)a0)[i];
    ushort4 o;
    o.x = f2bf(v.x); o.y = f2bf(v.y); o.z = f2bf(v.z); o.w = f2bf(v.w);
    ((ushort4*)o0)[i] = o;
  } else if (bid < 7872) {            // w_qkv: row-permuted copy (q,k only)
    const int i = (bid - 6144) * 256 + tid;       // float4 index
    const int n = i / 192;                         // row (768/4 = 192 f4/row)
    const int c4 = i - n * 192;                    // float4 col within row
    int n2 = n;
    if (n < 1536) {
      const int d = n & 63;
      const int c = (((d & 1) | ((d >> 5) << 1)) << 4) | ((d >> 1) & 15);
      n2 = (n & ~63) | c;
    }
    const float4 v = ((const float4*)a1)[i];
    ushort4 o;
    o.x = f2bf(v.x); o.y = f2bf(v.y); o.z = f2bf(v.z); o.w = f2bf(v.w);
    ((ushort4*)o1)[n2 * 192 + c4] = o;
  } else {                            // w_o: flat copy
    const int i = (bid - 7872) * 256 + tid;
    const float4 v = ((const float4*)a2)[i];
    ushort4 o;
    o.x = f2bf(v.x); o.y = f2bf(v.y); o.z = f2bf(v.z); o.w = f2bf(v.w);
    ((ushort4*)o2)[i] = o;
  }
}

// ---------------- GEMM: C[m,n] = sum_k A[m,k]*Bt[n,k]  (bf16 in)
// BM=64, BN=128, BK=64, XOR-swizzled LDS, 4 waves (each 64r x 32c), 16x16x32
// MFMA, XCD swizzle.  Double-buffered, 2-barrier counted-vmcnt(6) schedule.
// 48 KB LDS -> 3 blocks/CU = 12 waves sustained; bank conflicts = 0.
// setprio REMOVED (T5 measured null-to-negative on barrier-locked GEMMs, m190).
// MODE 1: f32 C out (grid 6x128).  MODE 2 (grid 18x128): fused qkv epilogue --
// rope+relayout q,k to (b,h,t,d) bf16 (q pre-scaled by 0.125*log2e);
// v-section transposes in the dead B-staging LDS and writes Vt (b,h,d,t).
template<int MODE>
__global__ __launch_bounds__(256) void k_gemm_bt(const u16* __restrict__ A,
                                                 const u16* __restrict__ Bt,
                                                 float* __restrict__ Cout,
                                                 u16* __restrict__ qout,
                                                 u16* __restrict__ kout,
                                                 u16* __restrict__ vtout,
                                                 const float* __restrict__ rope,
                                                 int M, int N, int K) {
  __shared__ u16 lA[2 * 64 * 64];
  __shared__ u16 lB[2 * 128 * 64];
  const int tid = threadIdx.x;
  const int l = tid & 63, w = tid >> 6;
  const int lo = l & 15, hi = l >> 4;
  const int wcol = w * 32;
  const int pid = blockIdx.x + gridDim.x * blockIdx.y;
  const int total = gridDim.x * gridDim.y;
  const int lid = (pid & 7) * (total >> 3) + (pid >> 3);
  const int bx = lid % gridDim.x, by = lid / gridDim.x;
  const int m0 = by * 64, n0 = bx * 128;

  // staging: thread t, pass p stages row (t>>3)+32p, 16B at swizzled source
  // col scb = ((t&7)*16) ^ ((row&7)<<4); dest linear (8t + 2048p elements).
  const int srow_t = tid >> 3;
  const int scb   = ((tid & 7) * 16) ^ ((srow_t & 7) << 4);
  const int swz   = (lo & 7) << 4;            // read-side XOR (row&7 == lo&7)

  auto STAGE = [&](int bufi, int k0) {
#pragma unroll
    for (int p = 0; p < 2; ++p)
      __builtin_amdgcn_global_load_lds(
          (gas_t)(u16*)(A + (size_t)(m0 + srow_t + 32 * p) * K + k0 + (scb >> 1)),
          (las_t)(lA + bufi * 64 * 64 + p * 2048 + tid * 8), 16, 0, 0);
#pragma unroll
    for (int p = 0; p < 4; ++p)
      __builtin_amdgcn_global_load_lds(
          (gas_t)(u16*)(Bt + (size_t)(n0 + srow_t + 32 * p) * K + k0 + (scb >> 1)),
          (las_t)(lB + bufi * 128 * 64 + p * 2048 + tid * 8), 16, 0, 0);
  };

  f32x4 acc[4][2] = {};
  auto COMPUTE = [&](const u16* la, const u16* lb) {
#pragma unroll
    for (int kk = 0; kk < 2; ++kk) {
      const int co = ((kk * 64 + hi * 16) ^ swz) >> 1;   // element col offset
      bf16x8 af[4], bfr[2];
#pragma unroll
      for (int i = 0; i < 4; ++i)
        af[i] = *(const bf16x8*)(la + (i * 16 + lo) * 64 + co);
#pragma unroll
      for (int j = 0; j < 2; ++j)
        bfr[j] = *(const bf16x8*)(lb + (wcol + j * 16 + lo) * 64 + co);
#pragma unroll
      for (int i = 0; i < 4; ++i)
#pragma unroll
        for (int j = 0; j < 2; ++j)
          acc[i][j] = __builtin_amdgcn_mfma_f32_16x16x32_bf16(af[i], bfr[j], acc[i][j], 0, 0, 0);
    }
  };

  // 2-barrier counted-vmcnt double-buffered K-loop (12 steps, K = 768)
  STAGE(0, 0);
  int cur = 0;
  const int nk = K >> 6;
  for (int ks = 0; ks < nk; ++ks) {
    if (ks + 1 < nk) {
      STAGE(cur ^ 1, (ks + 1) * 64);        // 6 loads, kept in flight
      asm volatile("s_waitcnt vmcnt(6)" ::: "memory");
    } else {
      asm volatile("s_waitcnt vmcnt(0)" ::: "memory");
    }
    __builtin_amdgcn_s_barrier();           // B1: buf[cur] ready for all
    __builtin_amdgcn_sched_barrier(0);
    COMPUTE(lA + cur * 64 * 64, lB + cur * 128 * 64);
    asm volatile("" ::: "memory");
    __builtin_amdgcn_s_barrier();           // B2: buf[cur] reads consumed
    __builtin_amdgcn_sched_barrier(0);
    cur ^= 1;
  }

  const int crow = m0;
  if (MODE == 1) {
#pragma unroll
    for (int i = 0; i < 4; ++i)
#pragma unroll
      for (int j = 0; j < 2; ++j)
#pragma unroll
        for (int r = 0; r < 4; ++r)
          Cout[(size_t)(crow + i * 16 + hi * 4 + r) * N + n0 + wcol + j * 16 + lo] = acc[i][j][r];
  } else {
    const int sect = bx / 6;              // 0 q, 1 k, 2 v  (uniform per block)
    if (sect < 2) {
      const int h2 = (bx % 6) * 2 + (w >> 1);   // head 0..11
      const int hp = w & 1;                 // 32-col half of the head
      // permuted cols: pair (acc[i][0][r], acc[i][1][r]) = x[d], x[d+1],
      // d = 2*ip, ip = hp*16 + lo (rope pair index)
      const float qsc = (sect == 0) ? 0.18033688011f : 1.0f;   // 0.125*log2(e)
      u16* dst = (sect == 0) ? qout : kout;
      const int ip = hp * 16 + lo;
#pragma unroll
      for (int i = 0; i < 4; ++i)
#pragma unroll
        for (int r = 0; r < 4; ++r) {
          const int trow = crow + i * 16 + hi * 4 + r;
          const int t = trow & (T_ - 1), bb = trow >> 11;
          const float2 cs = *(const float2*)(rope + ((size_t)t * 32 + ip) * 2);
          const float a0 = acc[i][0][r], a1 = acc[i][1][r];
          const float e0 = (a0 * cs.x - a1 * cs.y) * qsc;
          const float e1 = (a0 * cs.y + a1 * cs.x) * qsc;
          u16* row = dst + ((size_t)(bb * H_ + h2) * T_ + t) * D_;
          *(ushort2*)(row + 2 * ip) = make_ushort2(f2bf(e0), f2bf(e1));
        }
    } else {
      // v: transpose through LDS (reuse lB, dead after K-loop), write Vt
      // (b,h,d,t) directly.  lT layout [ncol 0..127][t 0..63], pad 72.
      u16* lT = lB;
      const int bb = crow >> 11;            // batch index
      const int t0 = crow & (T_ - 1);       // t-tile start WITHIN the batch
      const int hb = (bx % 6) * 2;          // head pair base
#pragma unroll
      for (int i = 0; i < 4; ++i)
#pragma unroll
        for (int j = 0; j < 2; ++j)
#pragma unroll
          for (int r = 0; r < 4; ++r)
            lT[(wcol + j * 16 + lo) * 72 + i * 16 + hi * 4 + r] = f2bf(acc[i][j][r]);
      __syncthreads();                      // block-uniform path: safe
#pragma unroll
      for (int pss = 0; pss < 4; ++pss) {
        const int row = pss * 32 + (tid >> 3);    // ncol 0..127
        const int toff = (tid & 7) * 8;           // t offset within tile
        const u32x4 vv = *(const u32x4*)(lT + row * 72 + toff);
        u16* dst = vtout + ((size_t)(bb * H_ + hb + (row >> 6)) * D_ + (row & 63)) * T_
                   + t0 + toff;
        *(u32x4*)dst = vv;
      }
    }
  }
}

// ---------------- flash attention v14: single barrier per kv-tile
// (unchanged -- uniform 33-tile blocks, kv-split waves, in-register P,
//  shift-free softmax, raw v_exp_f32, 4-way lsum; setprio kept: attn's
//  kv-split gives wave role diversity, T5's precondition)
__global__ __launch_bounds__(256) void k_attn(const u16* __restrict__ qb,
                                              const u16* __restrict__ kb,
                                              const u16* __restrict__ vtb,
                                              u16* __restrict__ yb) {
  __shared__ u16 kbuf[2][64 * 64];
  __shared__ u16 vbuf[2][64 * 64];
  __shared__ float obuf[2][64][33];      // stride 33 -> 2-way banking (free)
  __shared__ float lbuf[2][64];
  const int tid = threadIdx.x;
  const int w = tid >> 6, l = tid & 63;
  const int q5 = l & 31, hf = l >> 5;
  const int qg = w >> 1, st = w & 1;
  const int pid = blockIdx.x;
  const int xcd = pid & 7;
  const int rank = pid >> 3;                 // 0..95
  const int p = rank / 6;                    // 0..15 (segment pair)
  const int bh = xcd * 6 + rank % 6;         // 0..47 (6 heads per XCD L2)
  const int h = bh % H_, b = bh / H_;
  const u16* Q  = qb  + (size_t)bh * T_ * D_;
  const u16* K  = kb  + (size_t)bh * T_ * D_;
  const u16* Vt = vtb + (size_t)bh * D_ * T_;
  const int segA = 16 + p, segB = 15 - p;    // 64-q segment indices
  const int ntA = segA + 1;                  // tiles 0..segA; ntA+ntB = 33

  const int srow = tid >> 3;
  const int scb  = ((tid & 7) * 16) ^ ((srow & 7) << 4);
  const int swz  = (l & 7) << 4;

#define STAGE(bufi, j0s)                                                             \
  do {                                                                               \
    __builtin_amdgcn_global_load_lds((gas_t)(u16*)(K + (size_t)((j0s) + srow) * D_ + (scb >> 1)),      \
                                     (las_t)(&kbuf[bufi][0] + tid * 8), 16, 0, 0);   \
    __builtin_amdgcn_global_load_lds((gas_t)(u16*)(K + (size_t)((j0s) + 32 + srow) * D_ + (scb >> 1)), \
                                     (las_t)(&kbuf[bufi][0] + (tid + 256) * 8), 16, 0, 0);             \
    __builtin_amdgcn_global_load_lds((gas_t)(u16*)(Vt + (size_t)srow * T_ + (j0s) + (scb >> 1)),       \
                                     (las_t)(&vbuf[bufi][0] + tid * 8), 16, 0, 0);   \
    __builtin_amdgcn_global_load_lds((gas_t)(u16*)(Vt + (size_t)(32 + srow) * T_ + (j0s) + (scb >> 1)),\
                                     (las_t)(&vbuf[bufi][0] + (tid + 256) * 8), 16, 0, 0);             \
  } while (0)

  int seg = segA;
  int q0w = seg * 64 + qg * 32;
  int q = q0w + q5;                          // this lane's q column
  bf16x8 qf[4];
#pragma unroll
  for (int dc = 0; dc < 4; ++dc)
    qf[dc] = *(const bf16x8*)(Q + (size_t)q * D_ + dc * 16 + hf * 8);

  const f32x16 Z = {};
  f32x16 o0 = {}, o1 = {};                   // O^T rows d=0..31 / 32..63 (partial)
  float ls0 = 0.f, ls1 = 0.f, ls2 = 0.f, ls3 = 0.f;

  STAGE(0, 0);
  int cur = 0;
  for (int flat = 0; flat < 33; ++flat) {
    const int local = (flat < ntA) ? flat : flat - ntA;
    const int j0 = local * 64;
    // ---- single sync point: tile data ready AND prev-tile reads consumed
    asm volatile("s_waitcnt vmcnt(0)" ::: "memory");
    __builtin_amdgcn_s_barrier();
    __builtin_amdgcn_sched_barrier(0);
    if (flat + 1 < 33) {                     // prefetch next tile into buf^1
      const int nloc = (flat + 1 < ntA) ? flat + 1 : flat + 1 - ntA;
      STAGE(cur ^ 1, nloc * 64);
    }
    if (j0 + 32 * st <= q0w + 31) {          // wave has live kv columns
      const u16* kb_l = &kbuf[cur][0];
      const u16* vb_l = &vbuf[cur][0];
      // ---- QK^T: S[kv = j0+32st+row][q], chained over 4 d-chunks
      f32x16 s;
      __builtin_amdgcn_s_setprio(1);
      {
        const int krow = st * 32 + q5;
        const bf16x8 kd0 = *(const bf16x8*)(kb_l + krow * 64 + (((0  + 16 * hf) ^ swz) >> 1));
        s = __builtin_amdgcn_mfma_f32_32x32x16_bf16(kd0, qf[0], Z, 0, 0, 0);
        const bf16x8 kd1 = *(const bf16x8*)(kb_l + krow * 64 + (((32 + 16 * hf) ^ swz) >> 1));
        s = __builtin_amdgcn_mfma_f32_32x32x16_bf16(kd1, qf[1], s, 0, 0, 0);
        const bf16x8 kd2 = *(const bf16x8*)(kb_l + krow * 64 + (((64 + 16 * hf) ^ swz) >> 1));
        s = __builtin_amdgcn_mfma_f32_32x32x16_bf16(kd2, qf[2], s, 0, 0, 0);
        const bf16x8 kd3 = *(const bf16x8*)(kb_l + krow * 64 + (((96 + 16 * hf) ^ swz) >> 1));
        s = __builtin_amdgcn_mfma_f32_32x32x16_bf16(kd3, qf[3], s, 0, 0, 0);
      }
      __builtin_amdgcn_s_setprio(0);
      // ---- causal mask (diagonal tile only)
      if (local == seg) {
#pragma unroll
        for (int r = 0; r < 16; ++r) {
          const int kv = j0 + 32 * st + (r & 3) + 8 * (r >> 2) + 4 * hf;
          if (kv > q) s[r] = -1e30f;
        }
      }
      // ---- P = exp2(S) (q carries log2e/sqrt(D)); 4-way partial l
#pragma unroll
      for (int r = 0; r < 16; ++r)
        s[r] = __builtin_amdgcn_exp2f(s[r]);
#pragma unroll
      for (int r = 0; r < 16; r += 4) {
        ls0 += s[r]; ls1 += s[r + 1]; ls2 += s[r + 2]; ls3 += s[r + 3];
      }
      // ---- P -> bf16 PV B-fragments: cvt_pk + permlane32_swap
      u32 a0 = cvtpk(s[0],  s[1]),  b0 = cvtpk(s[4],  s[5]);  plswap(a0, b0);
      u32 a1 = cvtpk(s[2],  s[3]),  b1 = cvtpk(s[6],  s[7]);  plswap(a1, b1);
      u32 a2 = cvtpk(s[8],  s[9]),  b2 = cvtpk(s[12], s[13]); plswap(a2, b2);
      u32 a3 = cvtpk(s[10], s[11]), b3 = cvtpk(s[14], s[15]); plswap(a3, b3);
      const bf16x8 pa0 = __builtin_bit_cast(bf16x8, (u32x4){a0, a1, b0, b1});  // kv slot 2st
      const bf16x8 pa1 = __builtin_bit_cast(bf16x8, (u32x4){a2, a3, b2, b3});  // kv slot 2st+1
      // ---- PV: O^T[d][q] += Vt * P
      __builtin_amdgcn_s_setprio(1);
      {
        const int ks0 = st * 2, ks1 = st * 2 + 1;
        const bf16x8 vf00 = *(const bf16x8*)(vb_l + q5 * 64        + (((ks0 * 32 + 16 * hf) ^ swz) >> 1));
        const bf16x8 vf10 = *(const bf16x8*)(vb_l + (32 + q5) * 64 + (((ks0 * 32 + 16 * hf) ^ swz) >> 1));
        o0 = __builtin_amdgcn_mfma_f32_32x32x16_bf16(vf00, pa0, o0, 0, 0, 0);
        o1 = __builtin_amdgcn_mfma_f32_32x32x16_bf16(vf10, pa0, o1, 0, 0, 0);
        const bf16x8 vf01 = *(const bf16x8*)(vb_l + q5 * 64        + (((ks1 * 32 + 16 * hf) ^ swz) >> 1));
        const bf16x8 vf11 = *(const bf16x8*)(vb_l + (32 + q5) * 64 + (((ks1 * 32 + 16 * hf) ^ swz) >> 1));
        o0 = __builtin_amdgcn_mfma_f32_32x32x16_bf16(vf01, pa1, o0, 0, 0, 0);
        o1 = __builtin_amdgcn_mfma_f32_32x32x16_bf16(vf11, pa1, o1, 0, 0, 0);
      }
      __builtin_amdgcn_s_setprio(0);
    }
    // ---- segment end: combine kv-split partials (extra barrier, 2/block)
    if (local == seg) {
      if (st == 1) {                         // odd waves publish partials
        float* ob = &obuf[qg][l][0];
#pragma unroll
        for (int r = 0; r < 16; ++r) { ob[r] = o0[r]; ob[16 + r] = o1[r]; }
        float lr = (ls0 + ls1) + (ls2 + ls3);
        lr += __shfl_xor(lr, 32);
        lbuf[qg][l] = lr;
        asm volatile("s_waitcnt lgkmcnt(0)" ::: "memory");
      }
      asm volatile("" ::: "memory");
      __builtin_amdgcn_s_barrier();          // partials visible
      __builtin_amdgcn_sched_barrier(0);
      if (st == 0) {                         // even waves combine + store
        const float* ob = &obuf[qg][l][0];
#pragma unroll
        for (int r = 0; r < 16; ++r) { o0[r] += ob[r]; o1[r] += ob[16 + r]; }
        float lr = (ls0 + ls1) + (ls2 + ls3);
        lr += __shfl_xor(lr, 32);
        const float lt = lr + lbuf[qg][l];
        const float linv = 1.0f / lt;
        u16* yrow = yb + (size_t)(b * T_ + q) * C_ + h * D_;
#pragma unroll
        for (int g = 0; g < 4; ++g) {
          bf16x4 ok0, ok1;
#pragma unroll
          for (int r = 0; r < 4; ++r) {
            ok0[r] = (__bf16)(o0[4 * g + r] * linv);
            ok1[r] = (__bf16)(o1[4 * g + r] * linv);
          }
          *(bf16x4*)(yrow + g * 8 + 4 * hf)      = ok0;   // d = 8g+4hf+0..3
          *(bf16x4*)(yrow + 32 + g * 8 + 4 * hf) = ok1;   // d = 32+8g+4hf+0..3
        }
      }
      if (flat < 32) {                       // switch to light segment
        seg = segB;
        q0w = seg * 64 + qg * 32;
        q = q0w + q5;
#pragma unroll
        for (int dc = 0; dc < 4; ++dc)
          qf[dc] = *(const bf16x8*)(Q + (size_t)q * D_ + dc * 16 + hf * 8);
      }
      o0 = Z; o1 = Z;
      ls0 = 0.f; ls1 = 0.f; ls2 = 0.f; ls3 = 0.f;
    }
    cur ^= 1;
  }
#undef STAGE
}

extern "C" void kernel_launch(void* const* d_in, const int* in_sizes, int n_in,
                              void* d_out, int out_size, void* d_ws, size_t ws_size,
                              hipStream_t stream) {
  (void)in_sizes; (void)n_in; (void)out_size; (void)ws_size;
  const float* x    = (const float*)d_in[0];
  const float* rope = (const float*)d_in[1];
  const float* wqkv = (const float*)d_in[2];
  const float* wo   = (const float*)d_in[3];
  float* out = (float*)d_out;
  char* ws = (char*)d_ws;
  u16* xb    = (u16*)(ws);              // 12582912  (8192x768 bf16) -- reused as yb
  u16* wqkvb = (u16*)(ws + 12582912);   //  3538944  (2304x768, row-permuted)
  u16* wob   = (u16*)(ws + 16121856);   //  1179648  (768x768)
  u16* qb    = (u16*)(ws + 55050240);   // 12582912  (b,h,t,d)
  u16* kb    = (u16*)(ws + 67633152);   // 12582912  (b,h,t,d)
  u16* vtb   = (u16*)(ws + 80216064);   // 12582912  (b,h,d,t), written by GEMM epilogue
  u16* yb    = xb;                      // x is dead after QKV GEMM

  k_cvt3<<<8448, 256, 0, stream>>>(x, wqkv, wo, xb, wqkvb, wob);
  k_gemm_bt<2><<<dim3(18, 128), 256, 0, stream>>>(xb, wqkvb, nullptr, qb, kb, vtb,
                                                  rope, 8192, 2304, 768);
  k_attn<<<768, 256, 0, stream>>>(qb, kb, vtb, yb);
  k_gemm_bt<1><<<dim3(6, 128), 256, 0, stream>>>(yb, wob, out, nullptr, nullptr, nullptr,
                                                 nullptr, 8192, 768, 768);
}